// Round 9
// baseline (168.228 us; speedup 1.0000x reference)
//
#include <hip/hip_runtime.h>
#include <math.h>

// B=16, S=1024, E=320, H=8, DH=40 -> M = 16384 rows.
// bf16 MFMA everywhere. 6 launches:
//   L0 conv -> L1 G1(fp1|q|k|v) -> L2 {G2(bb) || attn} ->
//   L3 {fusedB(bb->t2->side) || G3(Wo)} ->
//   L4 {G7(pW1 -> t3, 640 blk) || fusedD(mW1->mW2->contact)} ->
//   L5 fusedC2(t3 -> c2(regs) -> refined)
// (r8 ran pW1 inside fusedC at 1 block/CU: barrier-bound, no co-resident
//  blocks to hide the vmcnt(0) drain. 640-block GEMM + light tail is faster.)

#define M_ROWS 16384

typedef float f32x4 __attribute__((ext_vector_type(4)));
typedef __bf16 bf16x8 __attribute__((ext_vector_type(8)));
typedef unsigned short ushort_t;

typedef const __attribute__((address_space(1))) void* gas_ptr;
typedef __attribute__((address_space(3))) void* las_ptr;

__device__ __forceinline__ unsigned int f2bf(float f) {
    union { float f; unsigned int u; } v; v.f = f;
    unsigned int u = v.u + 0x7FFFu + ((v.u >> 16) & 1u);   // RNE
    return u >> 16;
}
__device__ __forceinline__ float bf2f(ushort_t s) {
    union { unsigned int u; float f; } v; v.u = ((unsigned int)s) << 16;
    return v.f;
}

// ---------------------------------------------------------------------------
// GEMM core (verified r2/r3): BM=128, BK=64, 4 waves, mfma 16x16x32 bf16.
// LDS row-major [rows][64] bf16, unit-XOR swizzle by (row&7); global_load_lds
// dest linear, SOURCE column pre-swizzled (both-sides rule #21).
// ---------------------------------------------------------------------------
template<int BN>
__device__ __forceinline__ void gemm_core(
    int tx, int ty,
    const ushort_t* __restrict__ X1, const ushort_t* __restrict__ X2,
    int ksplit, int K, const ushort_t* __restrict__ W,
    char* smem, f32x4 (*acc)[2])
{
    constexpr int BM = 128, BK = 64;
    constexpr int WROWS = (BN == 64) ? 2 : 4;
    constexpr int WCOLS = 4 / WROWS;
    constexpr int WM = BM / WROWS;
    constexpr int WN = BN / WCOLS;   // 32
    constexpr int MF = WM / 16;
    constexpr int NF = WN / 16;      // 2

    ushort_t* As = (ushort_t*)smem;
    ushort_t* Bs = As + BM * BK;

    const int tid  = threadIdx.x;
    const int wave = tid >> 6;
    const int lane = tid & 63;
    const int m0 = ty * BM;
    const int n0 = tx * BN;
    const int wr = wave / WCOLS;
    const int wc = wave % WCOLS;
    const int sr = lane >> 3;
    const int su = lane & 7;

    for (int k0 = 0; k0 < K; k0 += BK) {
        #pragma unroll
        for (int i = 0; i < (BM * BK * 2) / 4096; ++i) {
            const int c = i * 4 + wave;
            const int r = c * 8 + sr;
            const int gk = k0 + (su ^ (r & 7)) * 8;
            const ushort_t* src;
            if (gk < ksplit) src = X1 + (size_t)(m0 + r) * ksplit + gk;
            else             src = X2 + (size_t)(m0 + r) * (K - ksplit) + (gk - ksplit);
            __builtin_amdgcn_global_load_lds((gas_ptr)src, (las_ptr)&As[c * 512], 16, 0, 0);
        }
        #pragma unroll
        for (int i = 0; i < (BN * BK * 2) / 4096; ++i) {
            const int c = i * 4 + wave;
            const int r = c * 8 + sr;
            const int gk = k0 + (su ^ (r & 7)) * 8;
            const ushort_t* src = W + (size_t)(n0 + r) * K + gk;
            __builtin_amdgcn_global_load_lds((gas_ptr)src, (las_ptr)&Bs[c * 512], 16, 0, 0);
        }
        __syncthreads();

        #pragma unroll
        for (int s = 0; s < 2; ++s) {
            bf16x8 a[MF], b[NF];
            #pragma unroll
            for (int mf = 0; mf < MF; ++mf) {
                const int r  = wr * WM + mf * 16 + (lane & 15);
                const int lu = (s * 4 + (lane >> 4)) ^ (r & 7);
                a[mf] = *reinterpret_cast<const bf16x8*>(&As[r * 64 + lu * 8]);
            }
            #pragma unroll
            for (int nf = 0; nf < NF; ++nf) {
                const int r  = wc * WN + nf * 16 + (lane & 15);
                const int lu = (s * 4 + (lane >> 4)) ^ (r & 7);
                b[nf] = *reinterpret_cast<const bf16x8*>(&Bs[r * 64 + lu * 8]);
            }
            #pragma unroll
            for (int mf = 0; mf < MF; ++mf)
                #pragma unroll
                for (int nf = 0; nf < NF; ++nf)
                    acc[mf][nf] = __builtin_amdgcn_mfma_f32_16x16x32_bf16(
                        a[mf], b[nf], acc[mf][nf], 0, 0, 0);
        }
        __syncthreads();
    }
}

template<int BN, bool RELU>
__device__ __forceinline__ void gemm_store(
    int tx, int ty, f32x4 (*acc)[2], const float* __restrict__ bias,
    float* __restrict__ outF, ushort_t* __restrict__ outB, int N)
{
    constexpr int WROWS = (BN == 64) ? 2 : 4;
    constexpr int WCOLS = 4 / WROWS;
    constexpr int WM = 128 / WROWS;
    constexpr int WN = BN / WCOLS;
    constexpr int MF = WM / 16;

    const int tid  = threadIdx.x;
    const int wave = tid >> 6;
    const int lane = tid & 63;
    const int wr = wave / WCOLS;
    const int wc = wave % WCOLS;

    #pragma unroll
    for (int nf = 0; nf < 2; ++nf) {
        const int gn = tx * BN + wc * WN + nf * 16 + (lane & 15);
        const float bv = bias[gn];
        #pragma unroll
        for (int mf = 0; mf < MF; ++mf) {
            #pragma unroll
            for (int i = 0; i < 4; ++i) {
                const int gm = ty * 128 + wr * WM + mf * 16 + (lane >> 4) * 4 + i;
                float v = acc[mf][nf][i] + bv;
                if (RELU) v = fmaxf(v, 0.f);
                if (outF) outF[(size_t)gm * N + gn] = v;
                if (outB) outB[(size_t)gm * N + gn] = (ushort_t)f2bf(v);
            }
        }
    }
}

template<int BN, bool RELU>
__device__ __forceinline__ void gemm_full(
    int bid, int ntx,
    const ushort_t* X1, const ushort_t* X2, int ksplit, int K,
    const ushort_t* W, const float* bias,
    float* outF, ushort_t* outB, int N, char* smem)
{
    const int tx = bid % ntx, ty = bid / ntx;
    constexpr int MF = (BN == 64) ? 4 : 2;
    f32x4 acc[MF][2];
    #pragma unroll
    for (int i = 0; i < MF; ++i) { acc[i][0] = (f32x4)0.f; acc[i][1] = (f32x4)0.f; }
    gemm_core<BN>(tx, ty, X1, X2, ksplit, K, W, smem, acc);
    gemm_store<BN, RELU>(tx, ty, acc, bias, outF, outB, N);
}

// --- attention over batch axis (per (s,h): 16x16 scores over DH=40) ---------
__device__ __forceinline__ void attn_dev(
    int ab, const ushort_t* __restrict__ qkv, ushort_t* __restrict__ ctx, char* smem)
{
    float* q_s = (float*)smem;            // [16][40]
    float* k_s = q_s + 16 * 40;
    float* v_s = k_s + 16 * 40;
    float* p_s = v_s + 16 * 40;           // [16][16]

    const int s   = ab >> 3;
    const int h   = ab & 7;
    const int tid = threadIdx.x;
    const int hb  = h * 40;

    for (int idx = tid; idx < 16 * 40; idx += 256) {
        int l = idx / 40, d = idx % 40;
        size_t row = (size_t)(l * 1024 + s) * 960;
        q_s[idx] = bf2f(qkv[row + hb + d]);
        k_s[idx] = bf2f(qkv[row + 320 + hb + d]);
        v_s[idx] = bf2f(qkv[row + 640 + hb + d]);
    }
    __syncthreads();

    {
        const int l = tid >> 4, m = tid & 15;
        float sc = 0.f;
        #pragma unroll
        for (int d = 0; d < 40; ++d) sc += q_s[l * 40 + d] * k_s[m * 40 + d];
        sc *= 0.15811388300841897f;   // 1/sqrt(40)
        float mx = sc;
        #pragma unroll
        for (int off = 1; off < 16; off <<= 1) mx = fmaxf(mx, __shfl_xor(mx, off, 16));
        float e = expf(sc - mx);
        float sum = e;
        #pragma unroll
        for (int off = 1; off < 16; off <<= 1) sum += __shfl_xor(sum, off, 16);
        p_s[l * 16 + m] = e / sum;
    }
    __syncthreads();

    for (int idx = tid; idx < 16 * 40; idx += 256) {
        int l = idx / 40, d = idx % 40;
        float acc = 0.f;
        #pragma unroll
        for (int m = 0; m < 16; ++m) acc += p_s[l * 16 + m] * v_s[m * 40 + d];
        ctx[(size_t)(l * 1024 + s) * 320 + hb + d] = (ushort_t)f2bf(acc);
    }
}

// ============================ fused panel kernels ===========================
// 64-row panels, 4 waves. Panel LDS tiles use the SAME [row][64]-with-
// (row&7)-XOR layout as As, so fragment reads are identical to gemm_core.

__device__ __forceinline__ void stage64(
    const ushort_t* __restrict__ src, int row0, int ldk, int k0,
    ushort_t* dst, int wave, int sr, int su)
{
    #pragma unroll
    for (int i = 0; i < 2; ++i) {
        const int c = i * 4 + wave;
        const int r = c * 8 + sr;
        const int gk = k0 + (su ^ (r & 7)) * 8;
        __builtin_amdgcn_global_load_lds(
            (gas_ptr)(src + (size_t)(row0 + r) * ldk + gk),
            (las_ptr)&dst[c * 512], 16, 0, 0);
    }
}
__device__ __forceinline__ void stage32(
    const ushort_t* __restrict__ src, int row0, int ldk, int k0,
    ushort_t* dst, int wave, int sr, int su)
{
    const int r = wave * 8 + sr;
    const int gk = k0 + (su ^ (r & 7)) * 8;
    __builtin_amdgcn_global_load_lds(
        (gas_ptr)(src + (size_t)(row0 + r) * ldk + gk),
        (las_ptr)&dst[wave * 512], 16, 0, 0);
}

// fusedB: t2 = relu(fp1 . bb) (LDS panel) ; side = fp2 . t2 -> fp32 + bf16
__device__ void fusedB_dev(
    int panel, const ushort_t* __restrict__ bbB,
    const ushort_t* __restrict__ fpW1b, const float* __restrict__ fpb1,
    const ushort_t* __restrict__ fpW2b, const float* __restrict__ fpb2,
    float* __restrict__ out_side, ushort_t* __restrict__ sideB, char* smem)
{
    ushort_t* tpan = (ushort_t*)smem;       // 5 ktiles x [64][64] = 40 KB
    ushort_t* As   = tpan + 5 * 4096;       // 8 KB
    ushort_t* Bs   = As + 4096;             // 8 KB

    const int tid = threadIdx.x, wave = tid >> 6, lane = tid & 63;
    const int row0 = panel * 64;
    const int wr = wave >> 1, wc = wave & 1;
    const int sr = lane >> 3, su = lane & 7;

    // phase 1: t2 panel
    for (int nb = 0; nb < 5; ++nb) {
        f32x4 acc[2][2];
        acc[0][0] = acc[0][1] = acc[1][0] = acc[1][1] = (f32x4)0.f;
        for (int k0 = 0; k0 < 320; k0 += 64) {
            stage64(bbB,   row0,    320, k0, As, wave, sr, su);
            stage64(fpW1b, nb * 64, 320, k0, Bs, wave, sr, su);
            __syncthreads();
            #pragma unroll
            for (int s = 0; s < 2; ++s) {
                bf16x8 a[2], b[2];
                #pragma unroll
                for (int mf = 0; mf < 2; ++mf) {
                    const int r  = wr * 32 + mf * 16 + (lane & 15);
                    const int lu = (s * 4 + (lane >> 4)) ^ (r & 7);
                    a[mf] = *reinterpret_cast<const bf16x8*>(&As[r * 64 + lu * 8]);
                }
                #pragma unroll
                for (int nf = 0; nf < 2; ++nf) {
                    const int r  = wc * 32 + nf * 16 + (lane & 15);
                    const int lu = (s * 4 + (lane >> 4)) ^ (r & 7);
                    b[nf] = *reinterpret_cast<const bf16x8*>(&Bs[r * 64 + lu * 8]);
                }
                #pragma unroll
                for (int mf = 0; mf < 2; ++mf)
                    #pragma unroll
                    for (int nf = 0; nf < 2; ++nf)
                        acc[mf][nf] = __builtin_amdgcn_mfma_f32_16x16x32_bf16(
                            a[mf], b[nf], acc[mf][nf], 0, 0, 0);
            }
            __syncthreads();
        }
        #pragma unroll
        for (int nf = 0; nf < 2; ++nf) {
            const int col = wc * 32 + nf * 16 + (lane & 15);
            const float bv = fpb1[nb * 64 + col];
            #pragma unroll
            for (int mf = 0; mf < 2; ++mf) {
                #pragma unroll
                for (int i = 0; i < 4; ++i) {
                    const int row = wr * 32 + mf * 16 + (lane >> 4) * 4 + i;
                    float v = fmaxf(acc[mf][nf][i] + bv, 0.f);
                    const int u = col >> 3;
                    tpan[nb * 4096 + row * 64 + ((u ^ (row & 7)) * 8) + (col & 7)]
                        = (ushort_t)f2bf(v);
                }
            }
        }
        __syncthreads();
    }

    // phase 2: side = t2 . fp2
    for (int nb = 0; nb < 5; ++nb) {
        f32x4 acc[2][2];
        acc[0][0] = acc[0][1] = acc[1][0] = acc[1][1] = (f32x4)0.f;
        for (int kt = 0; kt < 5; ++kt) {
            stage64(fpW2b, nb * 64, 320, kt * 64, Bs, wave, sr, su);
            __syncthreads();
            #pragma unroll
            for (int s = 0; s < 2; ++s) {
                bf16x8 a[2], b[2];
                #pragma unroll
                for (int mf = 0; mf < 2; ++mf) {
                    const int r  = wr * 32 + mf * 16 + (lane & 15);
                    const int lu = (s * 4 + (lane >> 4)) ^ (r & 7);
                    a[mf] = *reinterpret_cast<const bf16x8*>(&tpan[kt * 4096 + r * 64 + lu * 8]);
                }
                #pragma unroll
                for (int nf = 0; nf < 2; ++nf) {
                    const int r  = wc * 32 + nf * 16 + (lane & 15);
                    const int lu = (s * 4 + (lane >> 4)) ^ (r & 7);
                    b[nf] = *reinterpret_cast<const bf16x8*>(&Bs[r * 64 + lu * 8]);
                }
                #pragma unroll
                for (int mf = 0; mf < 2; ++mf)
                    #pragma unroll
                    for (int nf = 0; nf < 2; ++nf)
                        acc[mf][nf] = __builtin_amdgcn_mfma_f32_16x16x32_bf16(
                            a[mf], b[nf], acc[mf][nf], 0, 0, 0);
            }
            __syncthreads();
        }
        #pragma unroll
        for (int nf = 0; nf < 2; ++nf) {
            const int gn = nb * 64 + wc * 32 + nf * 16 + (lane & 15);
            const float bv = fpb2[gn];
            #pragma unroll
            for (int mf = 0; mf < 2; ++mf) {
                #pragma unroll
                for (int i = 0; i < 4; ++i) {
                    const int gm = row0 + wr * 32 + mf * 16 + (lane >> 4) * 4 + i;
                    float v = acc[mf][nf][i] + bv;
                    out_side[(size_t)gm * 320 + gn] = v;
                    sideB[(size_t)gm * 320 + gn] = (ushort_t)f2bf(v);
                }
            }
        }
    }
}

// fusedC2: stage t3 panel (64x320) once -> c2 = relu(pW2 . t3) in regs ->
//          refined = c2 . pW3 + pb3 via width-16 shfl reduce
__device__ void fusedC2_dev(
    int panel, const ushort_t* __restrict__ t3,
    const ushort_t* __restrict__ pW2b, const float* __restrict__ pb2,
    const float* __restrict__ pW3, const float* __restrict__ pb3,
    float* __restrict__ out_ref, char* smem)
{
    ushort_t* tpan = (ushort_t*)smem;       // 40 KB
    ushort_t* Bs   = tpan + 5 * 4096;       // 4 KB

    const int tid = threadIdx.x, wave = tid >> 6, lane = tid & 63;
    const int row0 = panel * 64;
    const int sr = lane >> 3, su = lane & 7;

    #pragma unroll
    for (int kt = 0; kt < 5; ++kt)
        stage64(t3, row0, 320, kt * 64, tpan + kt * 4096, wave, sr, su);
    __syncthreads();

    float part[4][3];
    #pragma unroll
    for (int i = 0; i < 4; ++i) { part[i][0] = part[i][1] = part[i][2] = 0.f; }

    for (int ct = 0; ct < 5; ++ct) {        // 32-col tiles of pW2 output
        f32x4 acc[2];
        acc[0] = acc[1] = (f32x4)0.f;
        for (int kt = 0; kt < 5; ++kt) {
            stage32(pW2b, ct * 32, 320, kt * 64, Bs, wave, sr, su);
            __syncthreads();
            #pragma unroll
            for (int s = 0; s < 2; ++s) {
                bf16x8 a, b[2];
                {
                    const int r  = wave * 16 + (lane & 15);
                    const int lu = (s * 4 + (lane >> 4)) ^ (r & 7);
                    a = *reinterpret_cast<const bf16x8*>(&tpan[kt * 4096 + r * 64 + lu * 8]);
                }
                #pragma unroll
                for (int nf = 0; nf < 2; ++nf) {
                    const int r  = nf * 16 + (lane & 15);
                    const int lu = (s * 4 + (lane >> 4)) ^ (r & 7);
                    b[nf] = *reinterpret_cast<const bf16x8*>(&Bs[r * 64 + lu * 8]);
                }
                #pragma unroll
                for (int nf = 0; nf < 2; ++nf)
                    acc[nf] = __builtin_amdgcn_mfma_f32_16x16x32_bf16(a, b[nf], acc[nf], 0, 0, 0);
            }
            __syncthreads();
        }
        #pragma unroll
        for (int nf = 0; nf < 2; ++nf) {
            const int col = ct * 32 + nf * 16 + (lane & 15);
            const float bv = pb2[col];
            #pragma unroll
            for (int i = 0; i < 4; ++i) {
                float v = fmaxf(acc[nf][i] + bv, 0.f);
                #pragma unroll
                for (int n = 0; n < 3; ++n)
                    part[i][n] += v * pW3[n * 160 + col];
            }
        }
    }
    #pragma unroll
    for (int off = 8; off; off >>= 1)
        #pragma unroll
        for (int i = 0; i < 4; ++i)
            #pragma unroll
            for (int n = 0; n < 3; ++n)
                part[i][n] += __shfl_xor(part[i][n], off, 16);
    if ((lane & 15) == 0) {
        #pragma unroll
        for (int i = 0; i < 4; ++i) {
            const int row = row0 + wave * 16 + (lane >> 4) * 4 + i;
            #pragma unroll
            for (int n = 0; n < 3; ++n)
                out_ref[(size_t)row * 3 + n] = part[i][n] + pb3[n];
        }
    }
}

// fusedD: c1 = relu(mW1 . ao) in regs ; prob = c1 . mW2 + mb2 ; contact rows
__device__ void fusedD_dev(
    int panel, const ushort_t* __restrict__ aoB,
    const ushort_t* __restrict__ mW1b, const float* __restrict__ mb1,
    const float* __restrict__ mW2, const float* __restrict__ mb2,
    float* __restrict__ out_cm, char* smem)
{
    ushort_t* As = (ushort_t*)smem;         // 8 KB
    ushort_t* Bs = As + 4096;               // 4 KB
    float* probs = (float*)(Bs + 2048);     // 64 floats

    const int tid = threadIdx.x, wave = tid >> 6, lane = tid & 63;
    const int row0 = panel * 64;
    const int sr = lane >> 3, su = lane & 7;

    float part[4] = {0.f, 0.f, 0.f, 0.f};

    for (int ct = 0; ct < 5; ++ct) {        // 32-col tiles of mW1 output
        f32x4 acc[2];
        acc[0] = acc[1] = (f32x4)0.f;
        for (int k0 = 0; k0 < 320; k0 += 64) {
            stage64(aoB,  row0,    320, k0, As, wave, sr, su);
            stage32(mW1b, ct * 32, 320, k0, Bs, wave, sr, su);
            __syncthreads();
            #pragma unroll
            for (int s = 0; s < 2; ++s) {
                bf16x8 a, b[2];
                {
                    const int r  = wave * 16 + (lane & 15);
                    const int lu = (s * 4 + (lane >> 4)) ^ (r & 7);
                    a = *reinterpret_cast<const bf16x8*>(&As[r * 64 + lu * 8]);
                }
                #pragma unroll
                for (int nf = 0; nf < 2; ++nf) {
                    const int r  = nf * 16 + (lane & 15);
                    const int lu = (s * 4 + (lane >> 4)) ^ (r & 7);
                    b[nf] = *reinterpret_cast<const bf16x8*>(&Bs[r * 64 + lu * 8]);
                }
                #pragma unroll
                for (int nf = 0; nf < 2; ++nf)
                    acc[nf] = __builtin_amdgcn_mfma_f32_16x16x32_bf16(a, b[nf], acc[nf], 0, 0, 0);
            }
            __syncthreads();
        }
        #pragma unroll
        for (int nf = 0; nf < 2; ++nf) {
            const int col = ct * 32 + nf * 16 + (lane & 15);
            const float bv = mb1[col];
            const float w  = mW2[col];
            #pragma unroll
            for (int i = 0; i < 4; ++i)
                part[i] += fmaxf(acc[nf][i] + bv, 0.f) * w;
        }
    }
    #pragma unroll
    for (int off = 8; off; off >>= 1)
        #pragma unroll
        for (int i = 0; i < 4; ++i)
            part[i] += __shfl_xor(part[i], off, 16);
    if ((lane & 15) == 0) {
        #pragma unroll
        for (int i = 0; i < 4; ++i)
            probs[wave * 16 + (lane >> 4) * 4 + i] = part[i] + mb2[0];
    }
    __syncthreads();

    for (int r = 0; r < 64; ++r) {
        const float p = probs[r];
        reinterpret_cast<float4*>(out_cm + (size_t)(row0 + r) * 1024)[tid] =
            make_float4(p, p, p, p);
    }
}

// ================================ kernels ===================================

struct ConvDesc { const float* src; ushort_t* dst; };
struct ConvPack { ConvDesc d[10]; int start[11]; };

__global__ __launch_bounds__(256) void conv_all(ConvPack p)
{
    const int bid = blockIdx.x;
    int i = 0;
    #pragma unroll
    for (int t = 0; t < 10; ++t) if (bid >= p.start[t + 1]) i = t + 1;
    const int local = bid - p.start[i];
    const int idx = (local * 256 + (int)threadIdx.x) * 4;
    float4 v = *reinterpret_cast<const float4*>(&p.d[i].src[idx]);
    unsigned int lo = f2bf(v.x) | (f2bf(v.y) << 16);
    unsigned int hi = f2bf(v.z) | (f2bf(v.w) << 16);
    *reinterpret_cast<uint2*>(&p.d[i].dst[idx]) = make_uint2(lo, hi);
}

// G1: x -> [fp1(relu) | q | k | v], N=1280 (verified r3)
__global__ __launch_bounds__(256) void k_g1(
    const ushort_t* __restrict__ xb, const ushort_t* __restrict__ Wcat,
    const float* __restrict__ fpb1, const float* __restrict__ bq,
    const float* __restrict__ bk, const float* __restrict__ bvv,
    ushort_t* __restrict__ t1b, ushort_t* __restrict__ qkvb)
{
    __shared__ __align__(16) char smem[24 * 1024];
    const int bid = blockIdx.x;
    const int tx = bid % 20, ty = bid / 20;
    f32x4 acc[4][2];
    #pragma unroll
    for (int i = 0; i < 4; ++i) { acc[i][0] = (f32x4)0.f; acc[i][1] = (f32x4)0.f; }
    gemm_core<64>(tx, ty, xb, xb, 320, 320, Wcat, smem, acc);

    const int tid = threadIdx.x, wave = tid >> 6, lane = tid & 63;
    const int wr = wave >> 1, wc = wave & 1;
    #pragma unroll
    for (int nf = 0; nf < 2; ++nf) {
        const int gn = tx * 64 + wc * 32 + nf * 16 + (lane & 15);
        float bv;
        if      (gn < 320) bv = fpb1[gn];
        else if (gn < 640) bv = bq[gn - 320];
        else if (gn < 960) bv = bk[gn - 640];
        else               bv = bvv[gn - 960];
        #pragma unroll
        for (int mf = 0; mf < 4; ++mf) {
            #pragma unroll
            for (int i = 0; i < 4; ++i) {
                const int gm = ty * 128 + wr * 64 + mf * 16 + (lane >> 4) * 4 + i;
                float v = acc[mf][nf][i] + bv;
                if (gn < 320) t1b [(size_t)gm * 320 + gn] = (ushort_t)f2bf(fmaxf(v, 0.f));
                else          qkvb[(size_t)gm * 960 + gn - 320] = (ushort_t)f2bf(v);
            }
        }
    }
}

// L2: [0,640) G2 (t1 -> fp2 -> bb), [640,8832) attention
__global__ __launch_bounds__(256) void k_g2_attn(
    const ushort_t* __restrict__ t1b, const ushort_t* __restrict__ fpW2b,
    const float* __restrict__ fpb2, float* __restrict__ out_bb,
    ushort_t* __restrict__ bbB,
    const ushort_t* __restrict__ qkvb, ushort_t* __restrict__ ctxb)
{
    __shared__ __align__(16) char smem[24 * 1024];
    const int bid = blockIdx.x;
    if (bid < 640) gemm_full<64, false>(bid, 5, t1b, t1b, 320, 320, fpW2b, fpb2, out_bb, bbB, 320, smem);
    else           attn_dev(bid - 640, qkvb, ctxb, smem);
}

// L3: [0,256) fusedB (bb -> t2 -> side), [256,896) G3 (ctx -> Wo -> ao)
__global__ __launch_bounds__(256) void k_l3(
    const ushort_t* __restrict__ bbB,
    const ushort_t* __restrict__ fpW1b, const float* __restrict__ fpb1,
    const ushort_t* __restrict__ fpW2b, const float* __restrict__ fpb2,
    float* __restrict__ out_side, ushort_t* __restrict__ sideB,
    const ushort_t* __restrict__ ctxb, const ushort_t* __restrict__ Wob,
    const float* __restrict__ bo, ushort_t* __restrict__ aoB)
{
    __shared__ __align__(16) char smem[56 * 1024];
    const int bid = blockIdx.x;
    if (bid < 256) fusedB_dev(bid, bbB, fpW1b, fpb1, fpW2b, fpb2, out_side, sideB, smem);
    else           gemm_full<64, false>(bid - 256, 5, ctxb, ctxb, 320, 320, Wob, bo, nullptr, aoB, 320, smem);
}

// L4: [0,640) G7 (pW1 GEMM, K=640 dual-input, -> t3), [640,896) fusedD
__global__ __launch_bounds__(256) void k_l4(
    const ushort_t* __restrict__ bbB, const ushort_t* __restrict__ sideB,
    const ushort_t* __restrict__ pW1b, const float* __restrict__ pb1,
    ushort_t* __restrict__ t3,
    const ushort_t* __restrict__ aoB,
    const ushort_t* __restrict__ mW1b, const float* __restrict__ mb1,
    const float* __restrict__ mW2, const float* __restrict__ mb2,
    float* __restrict__ out_cm)
{
    __shared__ __align__(16) char smem[24 * 1024];
    const int bid = blockIdx.x;
    if (bid < 640) gemm_full<64, true>(bid, 5, bbB, sideB, 320, 640, pW1b, pb1, nullptr, t3, 320, smem);
    else           fusedD_dev(bid - 640, aoB, mW1b, mb1, mW2, mb2, out_cm, smem);
}

// L5: fusedC2 (t3 -> c2(regs) -> refined)
__global__ __launch_bounds__(256) void k_l5(
    const ushort_t* __restrict__ t3,
    const ushort_t* __restrict__ pW2b, const float* __restrict__ pb2,
    const float* __restrict__ pW3, const float* __restrict__ pb3,
    float* __restrict__ out_ref)
{
    __shared__ __align__(16) char smem[48 * 1024];
    fusedC2_dev(blockIdx.x, t3, pW2b, pb2, pW3, pb3, out_ref, smem);
}

extern "C" void kernel_launch(void* const* d_in, const int* in_sizes, int n_in,
                              void* d_out, int out_size, void* d_ws, size_t ws_size,
                              hipStream_t stream)
{
    const float* x    = (const float*)d_in[0];
    const float* fpW1 = (const float*)d_in[1];
    const float* fpb1 = (const float*)d_in[2];
    const float* fpW2 = (const float*)d_in[3];
    const float* fpb2 = (const float*)d_in[4];
    const float* Wq   = (const float*)d_in[5];
    const float* bq   = (const float*)d_in[6];
    const float* Wk   = (const float*)d_in[7];
    const float* bk   = (const float*)d_in[8];
    const float* Wv   = (const float*)d_in[9];
    const float* bv   = (const float*)d_in[10];
    const float* Wo   = (const float*)d_in[11];
    const float* bo   = (const float*)d_in[12];
    const float* mW1  = (const float*)d_in[13];
    const float* mb1  = (const float*)d_in[14];
    const float* mW2  = (const float*)d_in[15];
    const float* mb2  = (const float*)d_in[16];
    const float* pW1  = (const float*)d_in[17];
    const float* pb1  = (const float*)d_in[18];
    const float* pW2  = (const float*)d_in[19];
    const float* pb2  = (const float*)d_in[20];
    const float* pW3  = (const float*)d_in[21];
    const float* pb3  = (const float*)d_in[22];

    float* out      = (float*)d_out;
    float* out_bb   = out;
    float* out_side = out + 5242880;
    float* out_cm   = out + 2 * 5242880;
    float* out_ref  = out + 2 * 5242880 + 16777216;

    ushort_t* ws = (ushort_t*)d_ws;
    const size_t BUF = 5242880;
    ushort_t* xb    = ws;              // x bf16; later ctx
    ushort_t* t1b   = ws + 1 * BUF;    // fp1(x) relu; later t3 (pW1 out)
    ushort_t* bbB   = ws + 2 * BUF;
    ushort_t* sideB = ws + 3 * BUF;
    ushort_t* qkvb  = ws + 4 * BUF;    // [M,960] spans 3 BUFs; later aoB
    ushort_t* wb    = ws + 7 * BUF;
    ushort_t* fpW1b = wb;              // Wcat = [fpW1|Wq|Wk|Wv] contiguous
    ushort_t* Wqb   = wb + 102400;
    ushort_t* Wkb   = wb + 204800;
    ushort_t* Wvb   = wb + 307200;
    ushort_t* fpW2b = wb + 409600;
    ushort_t* Wob   = wb + 512000;
    ushort_t* mW1b  = wb + 614400;
    ushort_t* pW1b  = wb + 665600;
    ushort_t* pW2b  = wb + 870400;

    ushort_t* ctxb = xb;               // aliases (lifetimes disjoint)
    ushort_t* aoB  = qkvb;
    ushort_t* t3   = t1b;

    dim3 blk(256);

    // L0: fp32 -> bf16 conversions (x + 9 weight matrices)
    ConvPack cp;
    const float* srcs[10] = {x, fpW1, Wq, Wk, Wv, fpW2, Wo, mW1, pW1, pW2};
    ushort_t*    dsts[10] = {xb, fpW1b, Wqb, Wkb, Wvb, fpW2b, Wob, mW1b, pW1b, pW2b};
    const int    nblk[10] = {5120, 100, 100, 100, 100, 100, 100, 50, 200, 50};
    int acc_blk = 0;
    for (int i = 0; i < 10; ++i) {
        cp.d[i].src = srcs[i]; cp.d[i].dst = dsts[i];
        cp.start[i] = acc_blk; acc_blk += nblk[i];
    }
    cp.start[10] = acc_blk;
    conv_all<<<dim3(acc_blk), blk, 0, stream>>>(cp);

    // L1: x -> [fp1 relu | q | k | v]
    k_g1<<<dim3(2560), blk, 0, stream>>>(xb, wb, fpb1, bq, bk, bv, t1b, qkvb);
    // L2: G2 (backbone) || attention
    k_g2_attn<<<dim3(8832), blk, 0, stream>>>(t1b, fpW2b, fpb2, out_bb, bbB, qkvb, ctxb);
    // L3: fusedB (side chain) || G3 (Wo proj)
    k_l3<<<dim3(896), blk, 0, stream>>>(bbB, fpW1b, fpb1, fpW2b, fpb2,
                                        out_side, sideB, ctxb, Wob, bo, aoB);
    // L4: G7 (pW1 -> t3, 640 blocks) || fusedD (contact)
    k_l4<<<dim3(896), blk, 0, stream>>>(bbB, sideB, pW1b, pb1, t3,
                                        aoB, mW1b, mb1, mW2, mb2, out_cm);
    // L5: fusedC2 (refined)
    k_l5<<<dim3(256), blk, 0, stream>>>(t3, pW2b, pb2, pW3, pb3, out_ref);
}

// Round 10
// 157.917 us; speedup vs baseline: 1.0653x; 1.0653x over previous
//
#include <hip/hip_runtime.h>
#include <math.h>

// B=16, S=1024, E=320, H=8, DH=40 -> M = 16384 rows.
// bf16 MFMA everywhere. 5 launches (r8 skeleton, 32-row fused panels):
//   L0 conv(x+Wcat) -> L1 {G1 || conv-rest} -> L2 {G2(bb) || attn} ->
//   L3 {fusedB32(bb->t2->side), 512 || G3(Wo), 640} ->
//   L4 {fusedC32(pW1->pW2->pW3->refined), 512 || fusedD(mW1->mW2->contact), 256}
// 32-row panels: 2x blocks + 32KB LDS (vs 56KB) -> 4-5 blocks/CU in L3/L4.

#define M_ROWS 16384

typedef float f32x4 __attribute__((ext_vector_type(4)));
typedef __bf16 bf16x8 __attribute__((ext_vector_type(8)));
typedef unsigned short ushort_t;

typedef const __attribute__((address_space(1))) void* gas_ptr;
typedef __attribute__((address_space(3))) void* las_ptr;

__device__ __forceinline__ unsigned int f2bf(float f) {
    union { float f; unsigned int u; } v; v.f = f;
    unsigned int u = v.u + 0x7FFFu + ((v.u >> 16) & 1u);   // RNE
    return u >> 16;
}
__device__ __forceinline__ float bf2f(ushort_t s) {
    union { unsigned int u; float f; } v; v.u = ((unsigned int)s) << 16;
    return v.f;
}

// ---------------------------------------------------------------------------
// GEMM core (verified r2/r3): BM=128, BK=64, 4 waves, mfma 16x16x32 bf16.
// LDS row-major [rows][64] bf16, unit-XOR swizzle by (row&7); global_load_lds
// dest linear, SOURCE column pre-swizzled (both-sides rule #21).
// ---------------------------------------------------------------------------
template<int BN>
__device__ __forceinline__ void gemm_core(
    int tx, int ty,
    const ushort_t* __restrict__ X1, const ushort_t* __restrict__ X2,
    int ksplit, int K, const ushort_t* __restrict__ W,
    char* smem, f32x4 (*acc)[2])
{
    constexpr int BM = 128, BK = 64;
    constexpr int WROWS = (BN == 64) ? 2 : 4;
    constexpr int WCOLS = 4 / WROWS;
    constexpr int WM = BM / WROWS;
    constexpr int WN = BN / WCOLS;   // 32
    constexpr int MF = WM / 16;
    constexpr int NF = WN / 16;      // 2

    ushort_t* As = (ushort_t*)smem;
    ushort_t* Bs = As + BM * BK;

    const int tid  = threadIdx.x;
    const int wave = tid >> 6;
    const int lane = tid & 63;
    const int m0 = ty * BM;
    const int n0 = tx * BN;
    const int wr = wave / WCOLS;
    const int wc = wave % WCOLS;
    const int sr = lane >> 3;
    const int su = lane & 7;

    for (int k0 = 0; k0 < K; k0 += BK) {
        #pragma unroll
        for (int i = 0; i < (BM * BK * 2) / 4096; ++i) {
            const int c = i * 4 + wave;
            const int r = c * 8 + sr;
            const int gk = k0 + (su ^ (r & 7)) * 8;
            const ushort_t* src;
            if (gk < ksplit) src = X1 + (size_t)(m0 + r) * ksplit + gk;
            else             src = X2 + (size_t)(m0 + r) * (K - ksplit) + (gk - ksplit);
            __builtin_amdgcn_global_load_lds((gas_ptr)src, (las_ptr)&As[c * 512], 16, 0, 0);
        }
        #pragma unroll
        for (int i = 0; i < (BN * BK * 2) / 4096; ++i) {
            const int c = i * 4 + wave;
            const int r = c * 8 + sr;
            const int gk = k0 + (su ^ (r & 7)) * 8;
            const ushort_t* src = W + (size_t)(n0 + r) * K + gk;
            __builtin_amdgcn_global_load_lds((gas_ptr)src, (las_ptr)&Bs[c * 512], 16, 0, 0);
        }
        __syncthreads();

        #pragma unroll
        for (int s = 0; s < 2; ++s) {
            bf16x8 a[MF], b[NF];
            #pragma unroll
            for (int mf = 0; mf < MF; ++mf) {
                const int r  = wr * WM + mf * 16 + (lane & 15);
                const int lu = (s * 4 + (lane >> 4)) ^ (r & 7);
                a[mf] = *reinterpret_cast<const bf16x8*>(&As[r * 64 + lu * 8]);
            }
            #pragma unroll
            for (int nf = 0; nf < NF; ++nf) {
                const int r  = wc * WN + nf * 16 + (lane & 15);
                const int lu = (s * 4 + (lane >> 4)) ^ (r & 7);
                b[nf] = *reinterpret_cast<const bf16x8*>(&Bs[r * 64 + lu * 8]);
            }
            #pragma unroll
            for (int mf = 0; mf < MF; ++mf)
                #pragma unroll
                for (int nf = 0; nf < NF; ++nf)
                    acc[mf][nf] = __builtin_amdgcn_mfma_f32_16x16x32_bf16(
                        a[mf], b[nf], acc[mf][nf], 0, 0, 0);
        }
        __syncthreads();
    }
}

template<int BN, bool RELU>
__device__ __forceinline__ void gemm_store(
    int tx, int ty, f32x4 (*acc)[2], const float* __restrict__ bias,
    float* __restrict__ outF, ushort_t* __restrict__ outB, int N)
{
    constexpr int WROWS = (BN == 64) ? 2 : 4;
    constexpr int WCOLS = 4 / WROWS;
    constexpr int WM = 128 / WROWS;
    constexpr int WN = BN / WCOLS;
    constexpr int MF = WM / 16;

    const int tid  = threadIdx.x;
    const int wave = tid >> 6;
    const int lane = tid & 63;
    const int wr = wave / WCOLS;
    const int wc = wave % WCOLS;

    #pragma unroll
    for (int nf = 0; nf < 2; ++nf) {
        const int gn = tx * BN + wc * WN + nf * 16 + (lane & 15);
        const float bv = bias[gn];
        #pragma unroll
        for (int mf = 0; mf < MF; ++mf) {
            #pragma unroll
            for (int i = 0; i < 4; ++i) {
                const int gm = ty * 128 + wr * WM + mf * 16 + (lane >> 4) * 4 + i;
                float v = acc[mf][nf][i] + bv;
                if (RELU) v = fmaxf(v, 0.f);
                if (outF) outF[(size_t)gm * N + gn] = v;
                if (outB) outB[(size_t)gm * N + gn] = (ushort_t)f2bf(v);
            }
        }
    }
}

template<int BN, bool RELU>
__device__ __forceinline__ void gemm_full(
    int bid, int ntx,
    const ushort_t* X1, const ushort_t* X2, int ksplit, int K,
    const ushort_t* W, const float* bias,
    float* outF, ushort_t* outB, int N, char* smem)
{
    const int tx = bid % ntx, ty = bid / ntx;
    constexpr int MF = (BN == 64) ? 4 : 2;
    f32x4 acc[MF][2];
    #pragma unroll
    for (int i = 0; i < MF; ++i) { acc[i][0] = (f32x4)0.f; acc[i][1] = (f32x4)0.f; }
    gemm_core<BN>(tx, ty, X1, X2, ksplit, K, W, smem, acc);
    gemm_store<BN, RELU>(tx, ty, acc, bias, outF, outB, N);
}

// --- attention over batch axis (per (s,h): 16x16 scores over DH=40) ---------
__device__ __forceinline__ void attn_dev(
    int ab, const ushort_t* __restrict__ qkv, ushort_t* __restrict__ ctx, char* smem)
{
    float* q_s = (float*)smem;            // [16][40]
    float* k_s = q_s + 16 * 40;
    float* v_s = k_s + 16 * 40;
    float* p_s = v_s + 16 * 40;           // [16][16]

    const int s   = ab >> 3;
    const int h   = ab & 7;
    const int tid = threadIdx.x;
    const int hb  = h * 40;

    for (int idx = tid; idx < 16 * 40; idx += 256) {
        int l = idx / 40, d = idx % 40;
        size_t row = (size_t)(l * 1024 + s) * 960;
        q_s[idx] = bf2f(qkv[row + hb + d]);
        k_s[idx] = bf2f(qkv[row + 320 + hb + d]);
        v_s[idx] = bf2f(qkv[row + 640 + hb + d]);
    }
    __syncthreads();

    {
        const int l = tid >> 4, m = tid & 15;
        float sc = 0.f;
        #pragma unroll
        for (int d = 0; d < 40; ++d) sc += q_s[l * 40 + d] * k_s[m * 40 + d];
        sc *= 0.15811388300841897f;   // 1/sqrt(40)
        float mx = sc;
        #pragma unroll
        for (int off = 1; off < 16; off <<= 1) mx = fmaxf(mx, __shfl_xor(mx, off, 16));
        float e = expf(sc - mx);
        float sum = e;
        #pragma unroll
        for (int off = 1; off < 16; off <<= 1) sum += __shfl_xor(sum, off, 16);
        p_s[l * 16 + m] = e / sum;
    }
    __syncthreads();

    for (int idx = tid; idx < 16 * 40; idx += 256) {
        int l = idx / 40, d = idx % 40;
        float acc = 0.f;
        #pragma unroll
        for (int m = 0; m < 16; ++m) acc += p_s[l * 16 + m] * v_s[m * 40 + d];
        ctx[(size_t)(l * 1024 + s) * 320 + hb + d] = (ushort_t)f2bf(acc);
    }
}

// ============================ fused panel kernels ===========================
// 32-row panels, 4 waves, wave grid 2x2 (16-row x 32-col per wave for 64-col
// tiles; 16x16 per wave for 32-col tiles). Panel LDS tiles use the SAME
// [row][64]-with-(row&7)-XOR layout as As -> identical fragment reads.

__device__ __forceinline__ void stage64(
    const ushort_t* __restrict__ src, int row0, int ldk, int k0,
    ushort_t* dst, int wave, int sr, int su)
{
    #pragma unroll
    for (int i = 0; i < 2; ++i) {
        const int c = i * 4 + wave;
        const int r = c * 8 + sr;
        const int gk = k0 + (su ^ (r & 7)) * 8;
        __builtin_amdgcn_global_load_lds(
            (gas_ptr)(src + (size_t)(row0 + r) * ldk + gk),
            (las_ptr)&dst[c * 512], 16, 0, 0);
    }
}
__device__ __forceinline__ void stage32(
    const ushort_t* __restrict__ src, int row0, int ldk, int k0,
    ushort_t* dst, int wave, int sr, int su)
{
    const int r = wave * 8 + sr;
    const int gk = k0 + (su ^ (r & 7)) * 8;
    __builtin_amdgcn_global_load_lds(
        (gas_ptr)(src + (size_t)(row0 + r) * ldk + gk),
        (las_ptr)&dst[wave * 512], 16, 0, 0);
}

// fusedB32: t2 = relu(fp1 . bb) (32-row LDS panel) ; side = fp2 . t2
__device__ void fusedB32_dev(
    int panel, const ushort_t* __restrict__ bbB,
    const ushort_t* __restrict__ fpW1b, const float* __restrict__ fpb1,
    const ushort_t* __restrict__ fpW2b, const float* __restrict__ fpb2,
    float* __restrict__ out_side, ushort_t* __restrict__ sideB, char* smem)
{
    ushort_t* tpan = (ushort_t*)smem;       // 5 x [32][64] = 20 KB
    ushort_t* As   = tpan + 5 * 2048;       // 4 KB
    ushort_t* Bs   = As + 2048;             // 8 KB

    const int tid = threadIdx.x, wave = tid >> 6, lane = tid & 63;
    const int row0 = panel * 32;
    const int wr = wave >> 1, wc = wave & 1;
    const int sr = lane >> 3, su = lane & 7;

    // phase 1: t2 panel (output 32x64 per nb; wave = 16 rows x 32 cols)
    for (int nb = 0; nb < 5; ++nb) {
        f32x4 acc[2]; acc[0] = (f32x4)0.f; acc[1] = (f32x4)0.f;
        for (int k0 = 0; k0 < 320; k0 += 64) {
            stage32(bbB,   row0,    320, k0, As, wave, sr, su);
            stage64(fpW1b, nb * 64, 320, k0, Bs, wave, sr, su);
            __syncthreads();
            #pragma unroll
            for (int s = 0; s < 2; ++s) {
                bf16x8 a, b[2];
                {
                    const int r  = wr * 16 + (lane & 15);
                    const int lu = (s * 4 + (lane >> 4)) ^ (r & 7);
                    a = *reinterpret_cast<const bf16x8*>(&As[r * 64 + lu * 8]);
                }
                #pragma unroll
                for (int nf = 0; nf < 2; ++nf) {
                    const int r  = wc * 32 + nf * 16 + (lane & 15);
                    const int lu = (s * 4 + (lane >> 4)) ^ (r & 7);
                    b[nf] = *reinterpret_cast<const bf16x8*>(&Bs[r * 64 + lu * 8]);
                }
                #pragma unroll
                for (int nf = 0; nf < 2; ++nf)
                    acc[nf] = __builtin_amdgcn_mfma_f32_16x16x32_bf16(a, b[nf], acc[nf], 0, 0, 0);
            }
            __syncthreads();
        }
        #pragma unroll
        for (int nf = 0; nf < 2; ++nf) {
            const int col = wc * 32 + nf * 16 + (lane & 15);
            const float bv = fpb1[nb * 64 + col];
            #pragma unroll
            for (int i = 0; i < 4; ++i) {
                const int row = wr * 16 + (lane >> 4) * 4 + i;
                float v = fmaxf(acc[nf][i] + bv, 0.f);
                const int u = col >> 3;
                tpan[nb * 2048 + row * 64 + ((u ^ (row & 7)) * 8) + (col & 7)]
                    = (ushort_t)f2bf(v);
            }
        }
        __syncthreads();
    }

    // phase 2: side = t2 . fp2
    for (int nb = 0; nb < 5; ++nb) {
        f32x4 acc[2]; acc[0] = (f32x4)0.f; acc[1] = (f32x4)0.f;
        for (int kt = 0; kt < 5; ++kt) {
            stage64(fpW2b, nb * 64, 320, kt * 64, Bs, wave, sr, su);
            __syncthreads();
            #pragma unroll
            for (int s = 0; s < 2; ++s) {
                bf16x8 a, b[2];
                {
                    const int r  = wr * 16 + (lane & 15);
                    const int lu = (s * 4 + (lane >> 4)) ^ (r & 7);
                    a = *reinterpret_cast<const bf16x8*>(&tpan[kt * 2048 + r * 64 + lu * 8]);
                }
                #pragma unroll
                for (int nf = 0; nf < 2; ++nf) {
                    const int r  = wc * 32 + nf * 16 + (lane & 15);
                    const int lu = (s * 4 + (lane >> 4)) ^ (r & 7);
                    b[nf] = *reinterpret_cast<const bf16x8*>(&Bs[r * 64 + lu * 8]);
                }
                #pragma unroll
                for (int nf = 0; nf < 2; ++nf)
                    acc[nf] = __builtin_amdgcn_mfma_f32_16x16x32_bf16(a, b[nf], acc[nf], 0, 0, 0);
            }
            __syncthreads();
        }
        #pragma unroll
        for (int nf = 0; nf < 2; ++nf) {
            const int gn = nb * 64 + wc * 32 + nf * 16 + (lane & 15);
            const float bv = fpb2[gn];
            #pragma unroll
            for (int i = 0; i < 4; ++i) {
                const int gm = row0 + wr * 16 + (lane >> 4) * 4 + i;
                float v = acc[nf][i] + bv;
                out_side[(size_t)gm * 320 + gn] = v;
                sideB[(size_t)gm * 320 + gn] = (ushort_t)f2bf(v);
            }
        }
    }
}

// fusedC32: t3 = relu(pW1 . [bb|side]) (32-row LDS panel, K=640) ;
//           c2 = relu(pW2 . t3) in regs ; refined = c2 . pW3 + pb3
__device__ void fusedC32_dev(
    int panel, const ushort_t* __restrict__ bbB, const ushort_t* __restrict__ sideB,
    const ushort_t* __restrict__ pW1b, const float* __restrict__ pb1,
    const ushort_t* __restrict__ pW2b, const float* __restrict__ pb2,
    const float* __restrict__ pW3, const float* __restrict__ pb3,
    float* __restrict__ out_ref, char* smem)
{
    ushort_t* tpan = (ushort_t*)smem;       // 20 KB
    ushort_t* As   = tpan + 5 * 2048;       // 4 KB
    ushort_t* Bs   = As + 2048;             // 8 KB
    float*    pSum = (float*)(Bs + 4096);   // [2][32][3] = 768 B

    const int tid = threadIdx.x, wave = tid >> 6, lane = tid & 63;
    const int row0 = panel * 32;
    const int wr = wave >> 1, wc = wave & 1;
    const int sr = lane >> 3, su = lane & 7;

    // phase 1: t3 panel (K=640 dual input)
    for (int nb = 0; nb < 5; ++nb) {
        f32x4 acc[2]; acc[0] = (f32x4)0.f; acc[1] = (f32x4)0.f;
        for (int k0 = 0; k0 < 640; k0 += 64) {
            {   // A: 32 rows dual-source, one chunk per wave
                const int r = wave * 8 + sr;
                const int gk = k0 + (su ^ (r & 7)) * 8;
                const ushort_t* src = (gk < 320)
                    ? bbB   + (size_t)(row0 + r) * 320 + gk
                    : sideB + (size_t)(row0 + r) * 320 + (gk - 320);
                __builtin_amdgcn_global_load_lds((gas_ptr)src, (las_ptr)&As[wave * 512], 16, 0, 0);
            }
            stage64(pW1b, nb * 64, 640, k0, Bs, wave, sr, su);
            __syncthreads();
            #pragma unroll
            for (int s = 0; s < 2; ++s) {
                bf16x8 a, b[2];
                {
                    const int r  = wr * 16 + (lane & 15);
                    const int lu = (s * 4 + (lane >> 4)) ^ (r & 7);
                    a = *reinterpret_cast<const bf16x8*>(&As[r * 64 + lu * 8]);
                }
                #pragma unroll
                for (int nf = 0; nf < 2; ++nf) {
                    const int r  = wc * 32 + nf * 16 + (lane & 15);
                    const int lu = (s * 4 + (lane >> 4)) ^ (r & 7);
                    b[nf] = *reinterpret_cast<const bf16x8*>(&Bs[r * 64 + lu * 8]);
                }
                #pragma unroll
                for (int nf = 0; nf < 2; ++nf)
                    acc[nf] = __builtin_amdgcn_mfma_f32_16x16x32_bf16(a, b[nf], acc[nf], 0, 0, 0);
            }
            __syncthreads();
        }
        #pragma unroll
        for (int nf = 0; nf < 2; ++nf) {
            const int col = wc * 32 + nf * 16 + (lane & 15);
            const float bv = pb1[nb * 64 + col];
            #pragma unroll
            for (int i = 0; i < 4; ++i) {
                const int row = wr * 16 + (lane >> 4) * 4 + i;
                float v = fmaxf(acc[nf][i] + bv, 0.f);
                const int u = col >> 3;
                tpan[nb * 2048 + row * 64 + ((u ^ (row & 7)) * 8) + (col & 7)]
                    = (ushort_t)f2bf(v);
            }
        }
        __syncthreads();
    }

    // phase 2: c2 tiles (32x32 per ct; wave = one 16x16 frag), pW3 partials
    float part[4][3];
    #pragma unroll
    for (int i = 0; i < 4; ++i) { part[i][0] = part[i][1] = part[i][2] = 0.f; }

    for (int ct = 0; ct < 5; ++ct) {
        f32x4 acc = (f32x4)0.f;
        for (int kt = 0; kt < 5; ++kt) {
            stage32(pW2b, ct * 32, 320, kt * 64, Bs, wave, sr, su);
            __syncthreads();
            #pragma unroll
            for (int s = 0; s < 2; ++s) {
                bf16x8 a, b;
                {
                    const int r  = wr * 16 + (lane & 15);
                    const int lu = (s * 4 + (lane >> 4)) ^ (r & 7);
                    a = *reinterpret_cast<const bf16x8*>(&tpan[kt * 2048 + r * 64 + lu * 8]);
                }
                {
                    const int r  = wc * 16 + (lane & 15);
                    const int lu = (s * 4 + (lane >> 4)) ^ (r & 7);
                    b = *reinterpret_cast<const bf16x8*>(&Bs[r * 64 + lu * 8]);
                }
                acc = __builtin_amdgcn_mfma_f32_16x16x32_bf16(a, b, acc, 0, 0, 0);
            }
            __syncthreads();
        }
        const int col = ct * 32 + wc * 16 + (lane & 15);
        const float bv = pb2[col];
        #pragma unroll
        for (int i = 0; i < 4; ++i) {
            float v = fmaxf(acc[i] + bv, 0.f);
            #pragma unroll
            for (int n = 0; n < 3; ++n)
                part[i][n] += v * pW3[n * 160 + col];
        }
    }
    // col-reduce within each 16-lane group, then cross-wc sum via LDS
    #pragma unroll
    for (int off = 8; off; off >>= 1)
        #pragma unroll
        for (int i = 0; i < 4; ++i)
            #pragma unroll
            for (int n = 0; n < 3; ++n)
                part[i][n] += __shfl_xor(part[i][n], off, 16);
    if ((lane & 15) == 0) {
        #pragma unroll
        for (int i = 0; i < 4; ++i) {
            const int row = wr * 16 + (lane >> 4) * 4 + i;
            #pragma unroll
            for (int n = 0; n < 3; ++n)
                pSum[(wc * 32 + row) * 3 + n] = part[i][n];
        }
    }
    __syncthreads();
    if (tid < 96) {
        const int row = tid / 3, n = tid % 3;
        out_ref[(size_t)(row0 + row) * 3 + n] =
            pSum[row * 3 + n] + pSum[(32 + row) * 3 + n] + pb3[n];
    }
}

// fusedD: c1 = relu(mW1 . ao) in regs ; prob = c1 . mW2 + mb2 ; contact rows
// (64-row panels, unchanged from r8 -- verified)
__device__ void fusedD_dev(
    int panel, const ushort_t* __restrict__ aoB,
    const ushort_t* __restrict__ mW1b, const float* __restrict__ mb1,
    const float* __restrict__ mW2, const float* __restrict__ mb2,
    float* __restrict__ out_cm, char* smem)
{
    ushort_t* As = (ushort_t*)smem;         // 8 KB
    ushort_t* Bs = As + 4096;               // 4 KB
    float* probs = (float*)(Bs + 2048);     // 64 floats

    const int tid = threadIdx.x, wave = tid >> 6, lane = tid & 63;
    const int row0 = panel * 64;
    const int sr = lane >> 3, su = lane & 7;

    float part[4] = {0.f, 0.f, 0.f, 0.f};

    for (int ct = 0; ct < 5; ++ct) {
        f32x4 acc[2];
        acc[0] = acc[1] = (f32x4)0.f;
        for (int k0 = 0; k0 < 320; k0 += 64) {
            stage64(aoB,  row0,    320, k0, As, wave, sr, su);
            stage32(mW1b, ct * 32, 320, k0, Bs, wave, sr, su);
            __syncthreads();
            #pragma unroll
            for (int s = 0; s < 2; ++s) {
                bf16x8 a, b[2];
                {
                    const int r  = wave * 16 + (lane & 15);
                    const int lu = (s * 4 + (lane >> 4)) ^ (r & 7);
                    a = *reinterpret_cast<const bf16x8*>(&As[r * 64 + lu * 8]);
                }
                #pragma unroll
                for (int nf = 0; nf < 2; ++nf) {
                    const int r  = nf * 16 + (lane & 15);
                    const int lu = (s * 4 + (lane >> 4)) ^ (r & 7);
                    b[nf] = *reinterpret_cast<const bf16x8*>(&Bs[r * 64 + lu * 8]);
                }
                #pragma unroll
                for (int nf = 0; nf < 2; ++nf)
                    acc[nf] = __builtin_amdgcn_mfma_f32_16x16x32_bf16(a, b[nf], acc[nf], 0, 0, 0);
            }
            __syncthreads();
        }
        #pragma unroll
        for (int nf = 0; nf < 2; ++nf) {
            const int col = ct * 32 + nf * 16 + (lane & 15);
            const float bv = mb1[col];
            const float w  = mW2[col];
            #pragma unroll
            for (int i = 0; i < 4; ++i)
                part[i] += fmaxf(acc[nf][i] + bv, 0.f) * w;
        }
    }
    #pragma unroll
    for (int off = 8; off; off >>= 1)
        #pragma unroll
        for (int i = 0; i < 4; ++i)
            part[i] += __shfl_xor(part[i], off, 16);
    if ((lane & 15) == 0) {
        #pragma unroll
        for (int i = 0; i < 4; ++i)
            probs[wave * 16 + (lane >> 4) * 4 + i] = part[i] + mb2[0];
    }
    __syncthreads();

    for (int r = 0; r < 64; ++r) {
        const float p = probs[r];
        reinterpret_cast<float4*>(out_cm + (size_t)(row0 + r) * 1024)[tid] =
            make_float4(p, p, p, p);
    }
}

// ================================ kernels ===================================

struct ConvDesc { const float* src; ushort_t* dst; };
struct ConvPack { ConvDesc d[5]; int start[6]; };

__device__ __forceinline__ void conv_unit(const ConvPack& p, int u, int tid)
{
    int i = 0;
    #pragma unroll
    for (int t = 0; t < 5; ++t) if (u >= p.start[t + 1]) i = t + 1;
    const int idx = ((u - p.start[i]) * 256 + tid) * 4;
    float4 v = *reinterpret_cast<const float4*>(&p.d[i].src[idx]);
    unsigned int lo = f2bf(v.x) | (f2bf(v.y) << 16);
    unsigned int hi = f2bf(v.z) | (f2bf(v.w) << 16);
    *reinterpret_cast<uint2*>(&p.d[i].dst[idx]) = make_uint2(lo, hi);
}

__global__ __launch_bounds__(256) void conv_k(ConvPack p)
{
    conv_unit(p, blockIdx.x, threadIdx.x);
}

// G1: x -> [fp1(relu) | q | k | v], N=1280 (verified r3).
// Blocks [2560, 2560+500): convert the 5 weight matrices later stages need.
__global__ __launch_bounds__(256) void k_g1(
    const ushort_t* __restrict__ xb, const ushort_t* __restrict__ Wcat,
    const float* __restrict__ fpb1, const float* __restrict__ bq,
    const float* __restrict__ bk, const float* __restrict__ bvv,
    ushort_t* __restrict__ t1b, ushort_t* __restrict__ qkvb, ConvPack cp)
{
    __shared__ __align__(16) char smem[24 * 1024];
    const int bid = blockIdx.x;
    if (bid >= 2560) { conv_unit(cp, bid - 2560, threadIdx.x); return; }

    const int tx = bid % 20, ty = bid / 20;
    f32x4 acc[4][2];
    #pragma unroll
    for (int i = 0; i < 4; ++i) { acc[i][0] = (f32x4)0.f; acc[i][1] = (f32x4)0.f; }
    gemm_core<64>(tx, ty, xb, xb, 320, 320, Wcat, smem, acc);

    const int tid = threadIdx.x, wave = tid >> 6, lane = tid & 63;
    const int wr = wave >> 1, wc = wave & 1;
    #pragma unroll
    for (int nf = 0; nf < 2; ++nf) {
        const int gn = tx * 64 + wc * 32 + nf * 16 + (lane & 15);
        float bv;
        if      (gn < 320) bv = fpb1[gn];
        else if (gn < 640) bv = bq[gn - 320];
        else if (gn < 960) bv = bk[gn - 640];
        else               bv = bvv[gn - 960];
        #pragma unroll
        for (int mf = 0; mf < 4; ++mf) {
            #pragma unroll
            for (int i = 0; i < 4; ++i) {
                const int gm = ty * 128 + wr * 64 + mf * 16 + (lane >> 4) * 4 + i;
                float v = acc[mf][nf][i] + bv;
                if (gn < 320) t1b [(size_t)gm * 320 + gn] = (ushort_t)f2bf(fmaxf(v, 0.f));
                else          qkvb[(size_t)gm * 960 + gn - 320] = (ushort_t)f2bf(v);
            }
        }
    }
}

// L2: [0,640) G2 (t1 -> fp2 -> bb), [640,8832) attention
__global__ __launch_bounds__(256) void k_g2_attn(
    const ushort_t* __restrict__ t1b, const ushort_t* __restrict__ fpW2b,
    const float* __restrict__ fpb2, float* __restrict__ out_bb,
    ushort_t* __restrict__ bbB,
    const ushort_t* __restrict__ qkvb, ushort_t* __restrict__ ctxb)
{
    __shared__ __align__(16) char smem[24 * 1024];
    const int bid = blockIdx.x;
    if (bid < 640) gemm_full<64, false>(bid, 5, t1b, t1b, 320, 320, fpW2b, fpb2, out_bb, bbB, 320, smem);
    else           attn_dev(bid - 640, qkvb, ctxb, smem);
}

// L3: [0,512) fusedB32 (bb -> t2 -> side), [512,1152) G3 (ctx -> Wo -> ao)
__global__ __launch_bounds__(256) void k_l3(
    const ushort_t* __restrict__ bbB,
    const ushort_t* __restrict__ fpW1b, const float* __restrict__ fpb1,
    const ushort_t* __restrict__ fpW2b, const float* __restrict__ fpb2,
    float* __restrict__ out_side, ushort_t* __restrict__ sideB,
    const ushort_t* __restrict__ ctxb, const ushort_t* __restrict__ Wob,
    const float* __restrict__ bo, ushort_t* __restrict__ aoB)
{
    __shared__ __align__(16) char smem[32 * 1024];
    const int bid = blockIdx.x;
    if (bid < 512) fusedB32_dev(bid, bbB, fpW1b, fpb1, fpW2b, fpb2, out_side, sideB, smem);
    else           gemm_full<64, false>(bid - 512, 5, ctxb, ctxb, 320, 320, Wob, bo, nullptr, aoB, 320, smem);
}

// L4: [0,512) fusedC32 (refined), [512,768) fusedD (contact)
__global__ __launch_bounds__(256) void k_l4(
    const ushort_t* __restrict__ bbB, const ushort_t* __restrict__ sideB,
    const ushort_t* __restrict__ pW1b, const float* __restrict__ pb1,
    const ushort_t* __restrict__ pW2b, const float* __restrict__ pb2,
    const float* __restrict__ pW3, const float* __restrict__ pb3,
    float* __restrict__ out_ref,
    const ushort_t* __restrict__ aoB,
    const ushort_t* __restrict__ mW1b, const float* __restrict__ mb1,
    const float* __restrict__ mW2, const float* __restrict__ mb2,
    float* __restrict__ out_cm)
{
    __shared__ __align__(16) char smem[34 * 1024];
    const int bid = blockIdx.x;
    if (bid < 512) fusedC32_dev(bid, bbB, sideB, pW1b, pb1, pW2b, pb2, pW3, pb3, out_ref, smem);
    else           fusedD_dev(bid - 512, aoB, mW1b, mb1, mW2, mb2, out_cm, smem);
}

extern "C" void kernel_launch(void* const* d_in, const int* in_sizes, int n_in,
                              void* d_out, int out_size, void* d_ws, size_t ws_size,
                              hipStream_t stream)
{
    const float* x    = (const float*)d_in[0];
    const float* fpW1 = (const float*)d_in[1];
    const float* fpb1 = (const float*)d_in[2];
    const float* fpW2 = (const float*)d_in[3];
    const float* fpb2 = (const float*)d_in[4];
    const float* Wq   = (const float*)d_in[5];
    const float* bq   = (const float*)d_in[6];
    const float* Wk   = (const float*)d_in[7];
    const float* bk   = (const float*)d_in[8];
    const float* Wv   = (const float*)d_in[9];
    const float* bv   = (const float*)d_in[10];
    const float* Wo   = (const float*)d_in[11];
    const float* bo   = (const float*)d_in[12];
    const float* mW1  = (const float*)d_in[13];
    const float* mb1  = (const float*)d_in[14];
    const float* mW2  = (const float*)d_in[15];
    const float* mb2  = (const float*)d_in[16];
    const float* pW1  = (const float*)d_in[17];
    const float* pb1  = (const float*)d_in[18];
    const float* pW2  = (const float*)d_in[19];
    const float* pb2  = (const float*)d_in[20];
    const float* pW3  = (const float*)d_in[21];
    const float* pb3  = (const float*)d_in[22];

    float* out      = (float*)d_out;
    float* out_bb   = out;
    float* out_side = out + 5242880;
    float* out_cm   = out + 2 * 5242880;
    float* out_ref  = out + 2 * 5242880 + 16777216;

    ushort_t* ws = (ushort_t*)d_ws;
    const size_t BUF = 5242880;
    ushort_t* xb    = ws;              // x bf16; later ctx
    ushort_t* t1b   = ws + 1 * BUF;    // fp1(x) relu
    ushort_t* bbB   = ws + 2 * BUF;
    ushort_t* sideB = ws + 3 * BUF;
    ushort_t* qkvb  = ws + 4 * BUF;    // [M,960] spans 3 BUFs; later aoB
    ushort_t* wb    = ws + 7 * BUF;
    ushort_t* fpW1b = wb;              // Wcat = [fpW1|Wq|Wk|Wv] contiguous
    ushort_t* Wqb   = wb + 102400;
    ushort_t* Wkb   = wb + 204800;
    ushort_t* Wvb   = wb + 307200;
    ushort_t* fpW2b = wb + 409600;
    ushort_t* Wob   = wb + 512000;
    ushort_t* mW1b  = wb + 614400;
    ushort_t* pW1b  = wb + 665600;
    ushort_t* pW2b  = wb + 870400;

    ushort_t* ctxb = xb;               // aliases (lifetimes disjoint)
    ushort_t* aoB  = qkvb;

    dim3 blk(256);

    // L0: convert x + Wcat (what G1 needs)
    ConvPack cp0;
    {
        const float* s[5] = {x, fpW1, Wq, Wk, Wv};
        ushort_t*    d[5] = {xb, fpW1b, Wqb, Wkb, Wvb};
        const int    n[5] = {5120, 100, 100, 100, 100};
        int a = 0;
        for (int i = 0; i < 5; ++i) { cp0.d[i] = {s[i], d[i]}; cp0.start[i] = a; a += n[i]; }
        cp0.start[5] = a;   // 5520
    }
    conv_k<<<dim3(5520), blk, 0, stream>>>(cp0);

    // L1: G1 (2560) || convert remaining 5 weight matrices (500)
    ConvPack cp1;
    {
        const float* s[5] = {fpW2, Wo, mW1, pW1, pW2};
        ushort_t*    d[5] = {fpW2b, Wob, mW1b, pW1b, pW2b};
        const int    n[5] = {100, 100, 50, 200, 50};
        int a = 0;
        for (int i = 0; i < 5; ++i) { cp1.d[i] = {s[i], d[i]}; cp1.start[i] = a; a += n[i]; }
        cp1.start[5] = a;   // 500
    }
    k_g1<<<dim3(2560 + 500), blk, 0, stream>>>(xb, wb, fpb1, bq, bk, bv, t1b, qkvb, cp1);

    // L2: G2 (backbone) || attention
    k_g2_attn<<<dim3(8832), blk, 0, stream>>>(t1b, fpW2b, fpb2, out_bb, bbB, qkvb, ctxb);
    // L3: fusedB32 (side chain, 512) || G3 (Wo proj, 640)
    k_l3<<<dim3(1152), blk, 0, stream>>>(bbB, fpW1b, fpb1, fpW2b, fpb2,
                                         out_side, sideB, ctxb, Wob, bo, aoB);
    // L4: fusedC32 (refined, 512) || fusedD (contact, 256)
    k_l4<<<dim3(768), blk, 0, stream>>>(bbB, sideB, pW1b, pb1, pW2b, pb2, pW3, pb3,
                                        out_ref, aoB, mW1b, mb1, mW2, mb2, out_cm);
}

// Round 11
// 148.650 us; speedup vs baseline: 1.1317x; 1.0623x over previous
//
#include <hip/hip_runtime.h>
#include <math.h>

// B=16, S=1024, E=320, H=8, DH=40 -> M = 16384 rows.
// bf16 MFMA everywhere. 5 launches (r10 skeleton + XCD-aware panel mapping):
//   L0 conv(x+Wcat) -> L1 {G1 || conv-rest} -> L2 {G2(bb) || attn} ->
//   L3 {fusedB32, 512 || G3(Wo), 640} -> L4 {fusedC32, 512 || fusedD, 256}
// XCD map (G1/G2/G3): xcd=bid&7, all tx-tiles of a row-panel on one XCD ->
// A-panel fetched from HBM once (r7 counter evidence: FETCH 93->24 MB).

#define M_ROWS 16384

typedef float f32x4 __attribute__((ext_vector_type(4)));
typedef __bf16 bf16x8 __attribute__((ext_vector_type(8)));
typedef unsigned short ushort_t;

typedef const __attribute__((address_space(1))) void* gas_ptr;
typedef __attribute__((address_space(3))) void* las_ptr;

__device__ __forceinline__ unsigned int f2bf(float f) {
    union { float f; unsigned int u; } v; v.f = f;
    unsigned int u = v.u + 0x7FFFu + ((v.u >> 16) & 1u);   // RNE
    return u >> 16;
}
__device__ __forceinline__ float bf2f(ushort_t s) {
    union { unsigned int u; float f; } v; v.u = ((unsigned int)s) << 16;
    return v.f;
}

// ---------------------------------------------------------------------------
// GEMM core (verified r2/r3): BM=128, BK=64, 4 waves, mfma 16x16x32 bf16.
// LDS row-major [rows][64] bf16, unit-XOR swizzle by (row&7); global_load_lds
// dest linear, SOURCE column pre-swizzled (both-sides rule #21).
// ---------------------------------------------------------------------------
template<int BN>
__device__ __forceinline__ void gemm_core(
    int tx, int ty,
    const ushort_t* __restrict__ X1, const ushort_t* __restrict__ X2,
    int ksplit, int K, const ushort_t* __restrict__ W,
    char* smem, f32x4 (*acc)[2])
{
    constexpr int BM = 128, BK = 64;
    constexpr int WROWS = (BN == 64) ? 2 : 4;
    constexpr int WCOLS = 4 / WROWS;
    constexpr int WM = BM / WROWS;
    constexpr int WN = BN / WCOLS;   // 32
    constexpr int MF = WM / 16;
    constexpr int NF = WN / 16;      // 2

    ushort_t* As = (ushort_t*)smem;
    ushort_t* Bs = As + BM * BK;

    const int tid  = threadIdx.x;
    const int wave = tid >> 6;
    const int lane = tid & 63;
    const int m0 = ty * BM;
    const int n0 = tx * BN;
    const int wr = wave / WCOLS;
    const int wc = wave % WCOLS;
    const int sr = lane >> 3;
    const int su = lane & 7;

    for (int k0 = 0; k0 < K; k0 += BK) {
        #pragma unroll
        for (int i = 0; i < (BM * BK * 2) / 4096; ++i) {
            const int c = i * 4 + wave;
            const int r = c * 8 + sr;
            const int gk = k0 + (su ^ (r & 7)) * 8;
            const ushort_t* src;
            if (gk < ksplit) src = X1 + (size_t)(m0 + r) * ksplit + gk;
            else             src = X2 + (size_t)(m0 + r) * (K - ksplit) + (gk - ksplit);
            __builtin_amdgcn_global_load_lds((gas_ptr)src, (las_ptr)&As[c * 512], 16, 0, 0);
        }
        #pragma unroll
        for (int i = 0; i < (BN * BK * 2) / 4096; ++i) {
            const int c = i * 4 + wave;
            const int r = c * 8 + sr;
            const int gk = k0 + (su ^ (r & 7)) * 8;
            const ushort_t* src = W + (size_t)(n0 + r) * K + gk;
            __builtin_amdgcn_global_load_lds((gas_ptr)src, (las_ptr)&Bs[c * 512], 16, 0, 0);
        }
        __syncthreads();

        #pragma unroll
        for (int s = 0; s < 2; ++s) {
            bf16x8 a[MF], b[NF];
            #pragma unroll
            for (int mf = 0; mf < MF; ++mf) {
                const int r  = wr * WM + mf * 16 + (lane & 15);
                const int lu = (s * 4 + (lane >> 4)) ^ (r & 7);
                a[mf] = *reinterpret_cast<const bf16x8*>(&As[r * 64 + lu * 8]);
            }
            #pragma unroll
            for (int nf = 0; nf < NF; ++nf) {
                const int r  = wc * WN + nf * 16 + (lane & 15);
                const int lu = (s * 4 + (lane >> 4)) ^ (r & 7);
                b[nf] = *reinterpret_cast<const bf16x8*>(&Bs[r * 64 + lu * 8]);
            }
            #pragma unroll
            for (int mf = 0; mf < MF; ++mf)
                #pragma unroll
                for (int nf = 0; nf < NF; ++nf)
                    acc[mf][nf] = __builtin_amdgcn_mfma_f32_16x16x32_bf16(
                        a[mf], b[nf], acc[mf][nf], 0, 0, 0);
        }
        __syncthreads();
    }
}

template<int BN, bool RELU>
__device__ __forceinline__ void gemm_store(
    int tx, int ty, f32x4 (*acc)[2], const float* __restrict__ bias,
    float* __restrict__ outF, ushort_t* __restrict__ outB, int N)
{
    constexpr int WROWS = (BN == 64) ? 2 : 4;
    constexpr int WCOLS = 4 / WROWS;
    constexpr int WM = 128 / WROWS;
    constexpr int WN = BN / WCOLS;
    constexpr int MF = WM / 16;

    const int tid  = threadIdx.x;
    const int wave = tid >> 6;
    const int lane = tid & 63;
    const int wr = wave / WCOLS;
    const int wc = wave % WCOLS;

    #pragma unroll
    for (int nf = 0; nf < 2; ++nf) {
        const int gn = tx * BN + wc * WN + nf * 16 + (lane & 15);
        const float bv = bias[gn];
        #pragma unroll
        for (int mf = 0; mf < MF; ++mf) {
            #pragma unroll
            for (int i = 0; i < 4; ++i) {
                const int gm = ty * 128 + wr * WM + mf * 16 + (lane >> 4) * 4 + i;
                float v = acc[mf][nf][i] + bv;
                if (RELU) v = fmaxf(v, 0.f);
                if (outF) outF[(size_t)gm * N + gn] = v;
                if (outB) outB[(size_t)gm * N + gn] = (ushort_t)f2bf(v);
            }
        }
    }
}

template<int BN, bool RELU>
__device__ __forceinline__ void gemm_full_xy(
    int tx, int ty,
    const ushort_t* X1, const ushort_t* X2, int ksplit, int K,
    const ushort_t* W, const float* bias,
    float* outF, ushort_t* outB, int N, char* smem)
{
    constexpr int MF = (BN == 64) ? 4 : 2;
    f32x4 acc[MF][2];
    #pragma unroll
    for (int i = 0; i < MF; ++i) { acc[i][0] = (f32x4)0.f; acc[i][1] = (f32x4)0.f; }
    gemm_core<BN>(tx, ty, X1, X2, ksplit, K, W, smem, acc);
    gemm_store<BN, RELU>(tx, ty, acc, bias, outF, outB, N);
}

// --- attention over batch axis (per (s,h): 16x16 scores over DH=40) ---------
// Loads vectorized bf16x8 (16B, aligned since 960/320/40 are all %8==0).
__device__ __forceinline__ void attn_dev(
    int ab, const ushort_t* __restrict__ qkv, ushort_t* __restrict__ ctx, char* smem)
{
    float* q_s = (float*)smem;            // [16][40]
    float* k_s = q_s + 16 * 40;
    float* v_s = k_s + 16 * 40;
    float* p_s = v_s + 16 * 40;           // [16][16]

    const int s   = ab >> 3;
    const int h   = ab & 7;
    const int tid = threadIdx.x;
    const int hb  = h * 40;

    if (tid < 240) {                      // 3 mats x 16 rows x 5 chunks of 8
        const int mat = tid / 80;
        const int rem = tid % 80;
        const int l = rem / 5, c8 = rem % 5;
        const size_t g = (size_t)(l * 1024 + s) * 960 + mat * 320 + hb + c8 * 8;
        bf16x8 vv = *reinterpret_cast<const bf16x8*>(&qkv[g]);
        const ushort_t* pu = reinterpret_cast<const ushort_t*>(&vv);
        float* dst = (mat == 0 ? q_s : mat == 1 ? k_s : v_s) + l * 40 + c8 * 8;
        #pragma unroll
        for (int j = 0; j < 8; ++j) dst[j] = bf2f(pu[j]);
    }
    __syncthreads();

    {
        const int l = tid >> 4, m = tid & 15;
        float sc = 0.f;
        #pragma unroll
        for (int d = 0; d < 40; ++d) sc += q_s[l * 40 + d] * k_s[m * 40 + d];
        sc *= 0.15811388300841897f;   // 1/sqrt(40)
        float mx = sc;
        #pragma unroll
        for (int off = 1; off < 16; off <<= 1) mx = fmaxf(mx, __shfl_xor(mx, off, 16));
        float e = expf(sc - mx);
        float sum = e;
        #pragma unroll
        for (int off = 1; off < 16; off <<= 1) sum += __shfl_xor(sum, off, 16);
        p_s[l * 16 + m] = e / sum;
    }
    __syncthreads();

    for (int idx = tid; idx < 16 * 40; idx += 256) {
        int l = idx / 40, d = idx % 40;
        float acc = 0.f;
        #pragma unroll
        for (int m = 0; m < 16; ++m) acc += p_s[l * 16 + m] * v_s[m * 40 + d];
        ctx[(size_t)(l * 1024 + s) * 320 + hb + d] = (ushort_t)f2bf(acc);
    }
}

// ============================ fused panel kernels ===========================
// 32-row panels, 4 waves. Panel LDS tiles use the SAME [row][64]-with-
// (row&7)-XOR layout as As -> identical fragment reads. (verified r10)

__device__ __forceinline__ void stage64(
    const ushort_t* __restrict__ src, int row0, int ldk, int k0,
    ushort_t* dst, int wave, int sr, int su)
{
    #pragma unroll
    for (int i = 0; i < 2; ++i) {
        const int c = i * 4 + wave;
        const int r = c * 8 + sr;
        const int gk = k0 + (su ^ (r & 7)) * 8;
        __builtin_amdgcn_global_load_lds(
            (gas_ptr)(src + (size_t)(row0 + r) * ldk + gk),
            (las_ptr)&dst[c * 512], 16, 0, 0);
    }
}
__device__ __forceinline__ void stage32(
    const ushort_t* __restrict__ src, int row0, int ldk, int k0,
    ushort_t* dst, int wave, int sr, int su)
{
    const int r = wave * 8 + sr;
    const int gk = k0 + (su ^ (r & 7)) * 8;
    __builtin_amdgcn_global_load_lds(
        (gas_ptr)(src + (size_t)(row0 + r) * ldk + gk),
        (las_ptr)&dst[wave * 512], 16, 0, 0);
}

// fusedB32: t2 = relu(fp1 . bb) (32-row LDS panel) ; side = fp2 . t2
__device__ void fusedB32_dev(
    int panel, const ushort_t* __restrict__ bbB,
    const ushort_t* __restrict__ fpW1b, const float* __restrict__ fpb1,
    const ushort_t* __restrict__ fpW2b, const float* __restrict__ fpb2,
    float* __restrict__ out_side, ushort_t* __restrict__ sideB, char* smem)
{
    ushort_t* tpan = (ushort_t*)smem;       // 5 x [32][64] = 20 KB
    ushort_t* As   = tpan + 5 * 2048;       // 4 KB
    ushort_t* Bs   = As + 2048;             // 8 KB

    const int tid = threadIdx.x, wave = tid >> 6, lane = tid & 63;
    const int row0 = panel * 32;
    const int wr = wave >> 1, wc = wave & 1;
    const int sr = lane >> 3, su = lane & 7;

    for (int nb = 0; nb < 5; ++nb) {
        f32x4 acc[2]; acc[0] = (f32x4)0.f; acc[1] = (f32x4)0.f;
        for (int k0 = 0; k0 < 320; k0 += 64) {
            stage32(bbB,   row0,    320, k0, As, wave, sr, su);
            stage64(fpW1b, nb * 64, 320, k0, Bs, wave, sr, su);
            __syncthreads();
            #pragma unroll
            for (int s = 0; s < 2; ++s) {
                bf16x8 a, b[2];
                {
                    const int r  = wr * 16 + (lane & 15);
                    const int lu = (s * 4 + (lane >> 4)) ^ (r & 7);
                    a = *reinterpret_cast<const bf16x8*>(&As[r * 64 + lu * 8]);
                }
                #pragma unroll
                for (int nf = 0; nf < 2; ++nf) {
                    const int r  = wc * 32 + nf * 16 + (lane & 15);
                    const int lu = (s * 4 + (lane >> 4)) ^ (r & 7);
                    b[nf] = *reinterpret_cast<const bf16x8*>(&Bs[r * 64 + lu * 8]);
                }
                #pragma unroll
                for (int nf = 0; nf < 2; ++nf)
                    acc[nf] = __builtin_amdgcn_mfma_f32_16x16x32_bf16(a, b[nf], acc[nf], 0, 0, 0);
            }
            __syncthreads();
        }
        #pragma unroll
        for (int nf = 0; nf < 2; ++nf) {
            const int col = wc * 32 + nf * 16 + (lane & 15);
            const float bv = fpb1[nb * 64 + col];
            #pragma unroll
            for (int i = 0; i < 4; ++i) {
                const int row = wr * 16 + (lane >> 4) * 4 + i;
                float v = fmaxf(acc[nf][i] + bv, 0.f);
                const int u = col >> 3;
                tpan[nb * 2048 + row * 64 + ((u ^ (row & 7)) * 8) + (col & 7)]
                    = (ushort_t)f2bf(v);
            }
        }
        __syncthreads();
    }

    for (int nb = 0; nb < 5; ++nb) {
        f32x4 acc[2]; acc[0] = (f32x4)0.f; acc[1] = (f32x4)0.f;
        for (int kt = 0; kt < 5; ++kt) {
            stage64(fpW2b, nb * 64, 320, kt * 64, Bs, wave, sr, su);
            __syncthreads();
            #pragma unroll
            for (int s = 0; s < 2; ++s) {
                bf16x8 a, b[2];
                {
                    const int r  = wr * 16 + (lane & 15);
                    const int lu = (s * 4 + (lane >> 4)) ^ (r & 7);
                    a = *reinterpret_cast<const bf16x8*>(&tpan[kt * 2048 + r * 64 + lu * 8]);
                }
                #pragma unroll
                for (int nf = 0; nf < 2; ++nf) {
                    const int r  = wc * 32 + nf * 16 + (lane & 15);
                    const int lu = (s * 4 + (lane >> 4)) ^ (r & 7);
                    b[nf] = *reinterpret_cast<const bf16x8*>(&Bs[r * 64 + lu * 8]);
                }
                #pragma unroll
                for (int nf = 0; nf < 2; ++nf)
                    acc[nf] = __builtin_amdgcn_mfma_f32_16x16x32_bf16(a, b[nf], acc[nf], 0, 0, 0);
            }
            __syncthreads();
        }
        #pragma unroll
        for (int nf = 0; nf < 2; ++nf) {
            const int gn = nb * 64 + wc * 32 + nf * 16 + (lane & 15);
            const float bv = fpb2[gn];
            #pragma unroll
            for (int i = 0; i < 4; ++i) {
                const int gm = row0 + wr * 16 + (lane >> 4) * 4 + i;
                float v = acc[nf][i] + bv;
                out_side[(size_t)gm * 320 + gn] = v;
                sideB[(size_t)gm * 320 + gn] = (ushort_t)f2bf(v);
            }
        }
    }
}

// fusedC32: t3 = relu(pW1 . [bb|side]) (32-row LDS panel, K=640) ;
//           c2 = relu(pW2 . t3) in regs ; refined = c2 . pW3 + pb3
__device__ void fusedC32_dev(
    int panel, const ushort_t* __restrict__ bbB, const ushort_t* __restrict__ sideB,
    const ushort_t* __restrict__ pW1b, const float* __restrict__ pb1,
    const ushort_t* __restrict__ pW2b, const float* __restrict__ pb2,
    const float* __restrict__ pW3, const float* __restrict__ pb3,
    float* __restrict__ out_ref, char* smem)
{
    ushort_t* tpan = (ushort_t*)smem;       // 20 KB
    ushort_t* As   = tpan + 5 * 2048;       // 4 KB
    ushort_t* Bs   = As + 2048;             // 8 KB
    float*    pSum = (float*)(Bs + 4096);   // [2][32][3]

    const int tid = threadIdx.x, wave = tid >> 6, lane = tid & 63;
    const int row0 = panel * 32;
    const int wr = wave >> 1, wc = wave & 1;
    const int sr = lane >> 3, su = lane & 7;

    for (int nb = 0; nb < 5; ++nb) {
        f32x4 acc[2]; acc[0] = (f32x4)0.f; acc[1] = (f32x4)0.f;
        for (int k0 = 0; k0 < 640; k0 += 64) {
            {
                const int r = wave * 8 + sr;
                const int gk = k0 + (su ^ (r & 7)) * 8;
                const ushort_t* src = (gk < 320)
                    ? bbB   + (size_t)(row0 + r) * 320 + gk
                    : sideB + (size_t)(row0 + r) * 320 + (gk - 320);
                __builtin_amdgcn_global_load_lds((gas_ptr)src, (las_ptr)&As[wave * 512], 16, 0, 0);
            }
            stage64(pW1b, nb * 64, 640, k0, Bs, wave, sr, su);
            __syncthreads();
            #pragma unroll
            for (int s = 0; s < 2; ++s) {
                bf16x8 a, b[2];
                {
                    const int r  = wr * 16 + (lane & 15);
                    const int lu = (s * 4 + (lane >> 4)) ^ (r & 7);
                    a = *reinterpret_cast<const bf16x8*>(&As[r * 64 + lu * 8]);
                }
                #pragma unroll
                for (int nf = 0; nf < 2; ++nf) {
                    const int r  = wc * 32 + nf * 16 + (lane & 15);
                    const int lu = (s * 4 + (lane >> 4)) ^ (r & 7);
                    b[nf] = *reinterpret_cast<const bf16x8*>(&Bs[r * 64 + lu * 8]);
                }
                #pragma unroll
                for (int nf = 0; nf < 2; ++nf)
                    acc[nf] = __builtin_amdgcn_mfma_f32_16x16x32_bf16(a, b[nf], acc[nf], 0, 0, 0);
            }
            __syncthreads();
        }
        #pragma unroll
        for (int nf = 0; nf < 2; ++nf) {
            const int col = wc * 32 + nf * 16 + (lane & 15);
            const float bv = pb1[nb * 64 + col];
            #pragma unroll
            for (int i = 0; i < 4; ++i) {
                const int row = wr * 16 + (lane >> 4) * 4 + i;
                float v = fmaxf(acc[nf][i] + bv, 0.f);
                const int u = col >> 3;
                tpan[nb * 2048 + row * 64 + ((u ^ (row & 7)) * 8) + (col & 7)]
                    = (ushort_t)f2bf(v);
            }
        }
        __syncthreads();
    }

    float part[4][3];
    #pragma unroll
    for (int i = 0; i < 4; ++i) { part[i][0] = part[i][1] = part[i][2] = 0.f; }

    for (int ct = 0; ct < 5; ++ct) {
        f32x4 acc = (f32x4)0.f;
        for (int kt = 0; kt < 5; ++kt) {
            stage32(pW2b, ct * 32, 320, kt * 64, Bs, wave, sr, su);
            __syncthreads();
            #pragma unroll
            for (int s = 0; s < 2; ++s) {
                bf16x8 a, b;
                {
                    const int r  = wr * 16 + (lane & 15);
                    const int lu = (s * 4 + (lane >> 4)) ^ (r & 7);
                    a = *reinterpret_cast<const bf16x8*>(&tpan[kt * 2048 + r * 64 + lu * 8]);
                }
                {
                    const int r  = wc * 16 + (lane & 15);
                    const int lu = (s * 4 + (lane >> 4)) ^ (r & 7);
                    b = *reinterpret_cast<const bf16x8*>(&Bs[r * 64 + lu * 8]);
                }
                acc = __builtin_amdgcn_mfma_f32_16x16x32_bf16(a, b, acc, 0, 0, 0);
            }
            __syncthreads();
        }
        const int col = ct * 32 + wc * 16 + (lane & 15);
        const float bv = pb2[col];
        #pragma unroll
        for (int i = 0; i < 4; ++i) {
            float v = fmaxf(acc[i] + bv, 0.f);
            #pragma unroll
            for (int n = 0; n < 3; ++n)
                part[i][n] += v * pW3[n * 160 + col];
        }
    }
    #pragma unroll
    for (int off = 8; off; off >>= 1)
        #pragma unroll
        for (int i = 0; i < 4; ++i)
            #pragma unroll
            for (int n = 0; n < 3; ++n)
                part[i][n] += __shfl_xor(part[i][n], off, 16);
    if ((lane & 15) == 0) {
        #pragma unroll
        for (int i = 0; i < 4; ++i) {
            const int row = wr * 16 + (lane >> 4) * 4 + i;
            #pragma unroll
            for (int n = 0; n < 3; ++n)
                pSum[(wc * 32 + row) * 3 + n] = part[i][n];
        }
    }
    __syncthreads();
    if (tid < 96) {
        const int row = tid / 3, n = tid % 3;
        out_ref[(size_t)(row0 + row) * 3 + n] =
            pSum[row * 3 + n] + pSum[(32 + row) * 3 + n] + pb3[n];
    }
}

// fusedD: c1 = relu(mW1 . ao) in regs ; prob = c1 . mW2 + mb2 ; contact rows
__device__ void fusedD_dev(
    int panel, const ushort_t* __restrict__ aoB,
    const ushort_t* __restrict__ mW1b, const float* __restrict__ mb1,
    const float* __restrict__ mW2, const float* __restrict__ mb2,
    float* __restrict__ out_cm, char* smem)
{
    ushort_t* As = (ushort_t*)smem;         // 8 KB
    ushort_t* Bs = As + 4096;               // 4 KB
    float* probs = (float*)(Bs + 2048);     // 64 floats

    const int tid = threadIdx.x, wave = tid >> 6, lane = tid & 63;
    const int row0 = panel * 64;
    const int sr = lane >> 3, su = lane & 7;

    float part[4] = {0.f, 0.f, 0.f, 0.f};

    for (int ct = 0; ct < 5; ++ct) {
        f32x4 acc[2];
        acc[0] = acc[1] = (f32x4)0.f;
        for (int k0 = 0; k0 < 320; k0 += 64) {
            stage64(aoB,  row0,    320, k0, As, wave, sr, su);
            stage32(mW1b, ct * 32, 320, k0, Bs, wave, sr, su);
            __syncthreads();
            #pragma unroll
            for (int s = 0; s < 2; ++s) {
                bf16x8 a, b[2];
                {
                    const int r  = wave * 16 + (lane & 15);
                    const int lu = (s * 4 + (lane >> 4)) ^ (r & 7);
                    a = *reinterpret_cast<const bf16x8*>(&As[r * 64 + lu * 8]);
                }
                #pragma unroll
                for (int nf = 0; nf < 2; ++nf) {
                    const int r  = nf * 16 + (lane & 15);
                    const int lu = (s * 4 + (lane >> 4)) ^ (r & 7);
                    b[nf] = *reinterpret_cast<const bf16x8*>(&Bs[r * 64 + lu * 8]);
                }
                #pragma unroll
                for (int nf = 0; nf < 2; ++nf)
                    acc[nf] = __builtin_amdgcn_mfma_f32_16x16x32_bf16(a, b[nf], acc[nf], 0, 0, 0);
            }
            __syncthreads();
        }
        #pragma unroll
        for (int nf = 0; nf < 2; ++nf) {
            const int col = ct * 32 + nf * 16 + (lane & 15);
            const float bv = mb1[col];
            const float w  = mW2[col];
            #pragma unroll
            for (int i = 0; i < 4; ++i)
                part[i] += fmaxf(acc[nf][i] + bv, 0.f) * w;
        }
    }
    #pragma unroll
    for (int off = 8; off; off >>= 1)
        #pragma unroll
        for (int i = 0; i < 4; ++i)
            part[i] += __shfl_xor(part[i], off, 16);
    if ((lane & 15) == 0) {
        #pragma unroll
        for (int i = 0; i < 4; ++i)
            probs[wave * 16 + (lane >> 4) * 4 + i] = part[i] + mb2[0];
    }
    __syncthreads();

    for (int r = 0; r < 64; ++r) {
        const float p = probs[r];
        reinterpret_cast<float4*>(out_cm + (size_t)(row0 + r) * 1024)[tid] =
            make_float4(p, p, p, p);
    }
}

// ================================ kernels ===================================

struct ConvDesc { const float* src; ushort_t* dst; };
struct ConvPack { ConvDesc d[5]; int start[6]; };

__device__ __forceinline__ void conv_unit(const ConvPack& p, int u, int tid)
{
    int i = 0;
    #pragma unroll
    for (int t = 0; t < 5; ++t) if (u >= p.start[t + 1]) i = t + 1;
    const int idx = ((u - p.start[i]) * 256 + tid) * 4;
    float4 v = *reinterpret_cast<const float4*>(&p.d[i].src[idx]);
    unsigned int lo = f2bf(v.x) | (f2bf(v.y) << 16);
    unsigned int hi = f2bf(v.z) | (f2bf(v.w) << 16);
    *reinterpret_cast<uint2*>(&p.d[i].dst[idx]) = make_uint2(lo, hi);
}

__global__ __launch_bounds__(256) void conv_k(ConvPack p)
{
    conv_unit(p, blockIdx.x, threadIdx.x);
}

// G1: x -> [fp1(relu) | q | k | v], N=1280, XCD-aware panel map.
// Blocks [2560, 2560+500): convert the 5 weight matrices later stages need.
__global__ __launch_bounds__(256) void k_g1(
    const ushort_t* __restrict__ xb, const ushort_t* __restrict__ Wcat,
    const float* __restrict__ fpb1, const float* __restrict__ bq,
    const float* __restrict__ bk, const float* __restrict__ bvv,
    ushort_t* __restrict__ t1b, ushort_t* __restrict__ qkvb, ConvPack cp)
{
    __shared__ __align__(16) char smem[24 * 1024];
    const int bid = blockIdx.x;
    if (bid >= 2560) { conv_unit(cp, bid - 2560, threadIdx.x); return; }

    // 2560 = 8 XCD x 16 panels x 20 tx; all 20 tx of a panel on one XCD
    const int xcd = bid & 7;
    const int i0  = bid >> 3;            // 0..319
    const int ty  = xcd * 16 + i0 / 20;  // 0..127
    const int tx  = i0 % 20;

    f32x4 acc[4][2];
    #pragma unroll
    for (int i = 0; i < 4; ++i) { acc[i][0] = (f32x4)0.f; acc[i][1] = (f32x4)0.f; }
    gemm_core<64>(tx, ty, xb, xb, 320, 320, Wcat, smem, acc);

    const int tid = threadIdx.x, wave = tid >> 6, lane = tid & 63;
    const int wr = wave >> 1, wc = wave & 1;
    #pragma unroll
    for (int nf = 0; nf < 2; ++nf) {
        const int gn = tx * 64 + wc * 32 + nf * 16 + (lane & 15);
        float bv;
        if      (gn < 320) bv = fpb1[gn];
        else if (gn < 640) bv = bq[gn - 320];
        else if (gn < 960) bv = bk[gn - 640];
        else               bv = bvv[gn - 960];
        #pragma unroll
        for (int mf = 0; mf < 4; ++mf) {
            #pragma unroll
            for (int i = 0; i < 4; ++i) {
                const int gm = ty * 128 + wr * 64 + mf * 16 + (lane >> 4) * 4 + i;
                float v = acc[mf][nf][i] + bv;
                if (gn < 320) t1b [(size_t)gm * 320 + gn] = (ushort_t)f2bf(fmaxf(v, 0.f));
                else          qkvb[(size_t)gm * 960 + gn - 320] = (ushort_t)f2bf(v);
            }
        }
    }
}

// L2: [0,640) G2 (t1 -> fp2 -> bb, XCD map), [640,8832) attention
__global__ __launch_bounds__(256) void k_g2_attn(
    const ushort_t* __restrict__ t1b, const ushort_t* __restrict__ fpW2b,
    const float* __restrict__ fpb2, float* __restrict__ out_bb,
    ushort_t* __restrict__ bbB,
    const ushort_t* __restrict__ qkvb, ushort_t* __restrict__ ctxb)
{
    __shared__ __align__(16) char smem[24 * 1024];
    const int bid = blockIdx.x;
    if (bid < 640) {
        const int xcd = bid & 7, i0 = bid >> 3;       // 640 = 8 x 16 x 5
        const int ty = xcd * 16 + i0 / 5, tx = i0 % 5;
        gemm_full_xy<64, false>(tx, ty, t1b, t1b, 320, 320, fpW2b, fpb2, out_bb, bbB, 320, smem);
    } else {
        attn_dev(bid - 640, qkvb, ctxb, smem);
    }
}

// L3: [0,512) fusedB32 (bb -> t2 -> side), [512,1152) G3 (ctx -> Wo -> ao, XCD map)
__global__ __launch_bounds__(256) void k_l3(
    const ushort_t* __restrict__ bbB,
    const ushort_t* __restrict__ fpW1b, const float* __restrict__ fpb1,
    const ushort_t* __restrict__ fpW2b, const float* __restrict__ fpb2,
    float* __restrict__ out_side, ushort_t* __restrict__ sideB,
    const ushort_t* __restrict__ ctxb, const ushort_t* __restrict__ Wob,
    const float* __restrict__ bo, ushort_t* __restrict__ aoB)
{
    __shared__ __align__(16) char smem[32 * 1024];
    const int bid = blockIdx.x;
    if (bid < 512) {
        fusedB32_dev(bid, bbB, fpW1b, fpb1, fpW2b, fpb2, out_side, sideB, smem);
    } else {
        const int b = bid - 512;
        const int xcd = b & 7, i0 = b >> 3;
        const int ty = xcd * 16 + i0 / 5, tx = i0 % 5;
        gemm_full_xy<64, false>(tx, ty, ctxb, ctxb, 320, 320, Wob, bo, nullptr, aoB, 320, smem);
    }
}

// L4: [0,512) fusedC32 (refined), [512,768) fusedD (contact)
__global__ __launch_bounds__(256) void k_l4(
    const ushort_t* __restrict__ bbB, const ushort_t* __restrict__ sideB,
    const ushort_t* __restrict__ pW1b, const float* __restrict__ pb1,
    const ushort_t* __restrict__ pW2b, const float* __restrict__ pb2,
    const float* __restrict__ pW3, const float* __restrict__ pb3,
    float* __restrict__ out_ref,
    const ushort_t* __restrict__ aoB,
    const ushort_t* __restrict__ mW1b, const float* __restrict__ mb1,
    const float* __restrict__ mW2, const float* __restrict__ mb2,
    float* __restrict__ out_cm)
{
    __shared__ __align__(16) char smem[34 * 1024];
    const int bid = blockIdx.x;
    if (bid < 512) fusedC32_dev(bid, bbB, sideB, pW1b, pb1, pW2b, pb2, pW3, pb3, out_ref, smem);
    else           fusedD_dev(bid - 512, aoB, mW1b, mb1, mW2, mb2, out_cm, smem);
}

extern "C" void kernel_launch(void* const* d_in, const int* in_sizes, int n_in,
                              void* d_out, int out_size, void* d_ws, size_t ws_size,
                              hipStream_t stream)
{
    const float* x    = (const float*)d_in[0];
    const float* fpW1 = (const float*)d_in[1];
    const float* fpb1 = (const float*)d_in[2];
    const float* fpW2 = (const float*)d_in[3];
    const float* fpb2 = (const float*)d_in[4];
    const float* Wq   = (const float*)d_in[5];
    const float* bq   = (const float*)d_in[6];
    const float* Wk   = (const float*)d_in[7];
    const float* bk   = (const float*)d_in[8];
    const float* Wv   = (const float*)d_in[9];
    const float* bv   = (const float*)d_in[10];
    const float* Wo   = (const float*)d_in[11];
    const float* bo   = (const float*)d_in[12];
    const float* mW1  = (const float*)d_in[13];
    const float* mb1  = (const float*)d_in[14];
    const float* mW2  = (const float*)d_in[15];
    const float* mb2  = (const float*)d_in[16];
    const float* pW1  = (const float*)d_in[17];
    const float* pb1  = (const float*)d_in[18];
    const float* pW2  = (const float*)d_in[19];
    const float* pb2  = (const float*)d_in[20];
    const float* pW3  = (const float*)d_in[21];
    const float* pb3  = (const float*)d_in[22];

    float* out      = (float*)d_out;
    float* out_bb   = out;
    float* out_side = out + 5242880;
    float* out_cm   = out + 2 * 5242880;
    float* out_ref  = out + 2 * 5242880 + 16777216;

    ushort_t* ws = (ushort_t*)d_ws;
    const size_t BUF = 5242880;
    ushort_t* xb    = ws;              // x bf16; later ctx
    ushort_t* t1b   = ws + 1 * BUF;    // fp1(x) relu
    ushort_t* bbB   = ws + 2 * BUF;
    ushort_t* sideB = ws + 3 * BUF;
    ushort_t* qkvb  = ws + 4 * BUF;    // [M,960] spans 3 BUFs; later aoB
    ushort_t* wb    = ws + 7 * BUF;
    ushort_t* fpW1b = wb;              // Wcat = [fpW1|Wq|Wk|Wv] contiguous
    ushort_t* Wqb   = wb + 102400;
    ushort_t* Wkb   = wb + 204800;
    ushort_t* Wvb   = wb + 307200;
    ushort_t* fpW2b = wb + 409600;
    ushort_t* Wob   = wb + 512000;
    ushort_t* mW1b  = wb + 614400;
    ushort_t* pW1b  = wb + 665600;
    ushort_t* pW2b  = wb + 870400;

    ushort_t* ctxb = xb;               // aliases (lifetimes disjoint)
    ushort_t* aoB  = qkvb;

    dim3 blk(256);

    // L0: convert x + Wcat (what G1 needs)
    ConvPack cp0;
    {
        const float* s[5] = {x, fpW1, Wq, Wk, Wv};
        ushort_t*    d[5] = {xb, fpW1b, Wqb, Wkb, Wvb};
        const int    n[5] = {5120, 100, 100, 100, 100};
        int a = 0;
        for (int i = 0; i < 5; ++i) { cp0.d[i] = {s[i], d[i]}; cp0.start[i] = a; a += n[i]; }
        cp0.start[5] = a;   // 5520
    }
    conv_k<<<dim3(5520), blk, 0, stream>>>(cp0);

    // L1: G1 (2560, XCD-aware) || convert remaining 5 weight matrices (500)
    ConvPack cp1;
    {
        const float* s[5] = {fpW2, Wo, mW1, pW1, pW2};
        ushort_t*    d[5] = {fpW2b, Wob, mW1b, pW1b, pW2b};
        const int    n[5] = {100, 100, 50, 200, 50};
        int a = 0;
        for (int i = 0; i < 5; ++i) { cp1.d[i] = {s[i], d[i]}; cp1.start[i] = a; a += n[i]; }
        cp1.start[5] = a;   // 500
    }
    k_g1<<<dim3(2560 + 500), blk, 0, stream>>>(xb, wb, fpb1, bq, bk, bv, t1b, qkvb, cp1);

    // L2: G2 (backbone, XCD-aware) || attention (vectorized loads)
    k_g2_attn<<<dim3(8832), blk, 0, stream>>>(t1b, fpW2b, fpb2, out_bb, bbB, qkvb, ctxb);
    // L3: fusedB32 (side chain, 512) || G3 (Wo proj, 640, XCD-aware)
    k_l3<<<dim3(1152), blk, 0, stream>>>(bbB, fpW1b, fpb1, fpW2b, fpb2,
                                         out_side, sideB, ctxb, Wob, bo, aoB);
    // L4: fusedC32 (refined, 512) || fusedD (contact, 256)
    k_l4<<<dim3(768), blk, 0, stream>>>(bbB, sideB, pW1b, pb1, pW2b, pb2, pW3, pb3,
                                        out_ref, aoB, mW1b, mb1, mW2, mb2, out_cm);
}

// Round 12
// 132.633 us; speedup vs baseline: 1.2684x; 1.1208x over previous
//
#include <hip/hip_runtime.h>
#include <math.h>

// B=16, S=1024, E=320, H=8, DH=40 -> M = 16384 rows.
// bf16 MFMA everywhere. 4 launches:
//   L0 conv(x+Wcat) -> L1 {G1 || conv-rest} ->
//   L2 {G2B(bb->t2->side, 512) || attn(8192)} ->
//   L3 {fusedC32(pW1->pW2->pW3->refined, 512) || fusedD32(Wo->mW1->mW2->contact, 512)}
// G2B chains G2+fusedB per panel (bb re-read via same-XCD L2);
// fusedD32 chains G3+fusedD per panel (ao lives only in LDS).

#define M_ROWS 16384

typedef float f32x4 __attribute__((ext_vector_type(4)));
typedef __bf16 bf16x8 __attribute__((ext_vector_type(8)));
typedef unsigned short ushort_t;

typedef const __attribute__((address_space(1))) void* gas_ptr;
typedef __attribute__((address_space(3))) void* las_ptr;

__device__ __forceinline__ unsigned int f2bf(float f) {
    union { float f; unsigned int u; } v; v.f = f;
    unsigned int u = v.u + 0x7FFFu + ((v.u >> 16) & 1u);   // RNE
    return u >> 16;
}
__device__ __forceinline__ float bf2f(ushort_t s) {
    union { unsigned int u; float f; } v; v.u = ((unsigned int)s) << 16;
    return v.f;
}

// ---------------------------------------------------------------------------
// GEMM core (verified r2/r3): BM=128, BK=64, 4 waves, mfma 16x16x32 bf16.
// LDS row-major [rows][64] bf16, unit-XOR swizzle by (row&7); global_load_lds
// dest linear, SOURCE column pre-swizzled (both-sides rule #21).
// ---------------------------------------------------------------------------
template<int BN>
__device__ __forceinline__ void gemm_core(
    int tx, int ty,
    const ushort_t* __restrict__ X1, const ushort_t* __restrict__ X2,
    int ksplit, int K, const ushort_t* __restrict__ W,
    char* smem, f32x4 (*acc)[2])
{
    constexpr int BM = 128, BK = 64;
    constexpr int WROWS = (BN == 64) ? 2 : 4;
    constexpr int WCOLS = 4 / WROWS;
    constexpr int WM = BM / WROWS;
    constexpr int WN = BN / WCOLS;   // 32
    constexpr int MF = WM / 16;
    constexpr int NF = WN / 16;      // 2

    ushort_t* As = (ushort_t*)smem;
    ushort_t* Bs = As + BM * BK;

    const int tid  = threadIdx.x;
    const int wave = tid >> 6;
    const int lane = tid & 63;
    const int m0 = ty * BM;
    const int n0 = tx * BN;
    const int wr = wave / WCOLS;
    const int wc = wave % WCOLS;
    const int sr = lane >> 3;
    const int su = lane & 7;

    for (int k0 = 0; k0 < K; k0 += BK) {
        #pragma unroll
        for (int i = 0; i < (BM * BK * 2) / 4096; ++i) {
            const int c = i * 4 + wave;
            const int r = c * 8 + sr;
            const int gk = k0 + (su ^ (r & 7)) * 8;
            const ushort_t* src;
            if (gk < ksplit) src = X1 + (size_t)(m0 + r) * ksplit + gk;
            else             src = X2 + (size_t)(m0 + r) * (K - ksplit) + (gk - ksplit);
            __builtin_amdgcn_global_load_lds((gas_ptr)src, (las_ptr)&As[c * 512], 16, 0, 0);
        }
        #pragma unroll
        for (int i = 0; i < (BN * BK * 2) / 4096; ++i) {
            const int c = i * 4 + wave;
            const int r = c * 8 + sr;
            const int gk = k0 + (su ^ (r & 7)) * 8;
            const ushort_t* src = W + (size_t)(n0 + r) * K + gk;
            __builtin_amdgcn_global_load_lds((gas_ptr)src, (las_ptr)&Bs[c * 512], 16, 0, 0);
        }
        __syncthreads();

        #pragma unroll
        for (int s = 0; s < 2; ++s) {
            bf16x8 a[MF], b[NF];
            #pragma unroll
            for (int mf = 0; mf < MF; ++mf) {
                const int r  = wr * WM + mf * 16 + (lane & 15);
                const int lu = (s * 4 + (lane >> 4)) ^ (r & 7);
                a[mf] = *reinterpret_cast<const bf16x8*>(&As[r * 64 + lu * 8]);
            }
            #pragma unroll
            for (int nf = 0; nf < NF; ++nf) {
                const int r  = wc * WN + nf * 16 + (lane & 15);
                const int lu = (s * 4 + (lane >> 4)) ^ (r & 7);
                b[nf] = *reinterpret_cast<const bf16x8*>(&Bs[r * 64 + lu * 8]);
            }
            #pragma unroll
            for (int mf = 0; mf < MF; ++mf)
                #pragma unroll
                for (int nf = 0; nf < NF; ++nf)
                    acc[mf][nf] = __builtin_amdgcn_mfma_f32_16x16x32_bf16(
                        a[mf], b[nf], acc[mf][nf], 0, 0, 0);
        }
        __syncthreads();
    }
}

// --- attention over batch axis (per (s,h): 16x16 scores over DH=40) ---------
__device__ __forceinline__ void attn_dev(
    int ab, const ushort_t* __restrict__ qkv, ushort_t* __restrict__ ctx, char* smem)
{
    float* q_s = (float*)smem;            // [16][40]
    float* k_s = q_s + 16 * 40;
    float* v_s = k_s + 16 * 40;
    float* p_s = v_s + 16 * 40;           // [16][16]

    const int s   = ab >> 3;
    const int h   = ab & 7;
    const int tid = threadIdx.x;
    const int hb  = h * 40;

    if (tid < 240) {                      // 3 mats x 16 rows x 5 chunks of 8
        const int mat = tid / 80;
        const int rem = tid % 80;
        const int l = rem / 5, c8 = rem % 5;
        const size_t g = (size_t)(l * 1024 + s) * 960 + mat * 320 + hb + c8 * 8;
        bf16x8 vv = *reinterpret_cast<const bf16x8*>(&qkv[g]);
        const ushort_t* pu = reinterpret_cast<const ushort_t*>(&vv);
        float* dst = (mat == 0 ? q_s : mat == 1 ? k_s : v_s) + l * 40 + c8 * 8;
        #pragma unroll
        for (int j = 0; j < 8; ++j) dst[j] = bf2f(pu[j]);
    }
    __syncthreads();

    {
        const int l = tid >> 4, m = tid & 15;
        float sc = 0.f;
        #pragma unroll
        for (int d = 0; d < 40; ++d) sc += q_s[l * 40 + d] * k_s[m * 40 + d];
        sc *= 0.15811388300841897f;   // 1/sqrt(40)
        float mx = sc;
        #pragma unroll
        for (int off = 1; off < 16; off <<= 1) mx = fmaxf(mx, __shfl_xor(mx, off, 16));
        float e = expf(sc - mx);
        float sum = e;
        #pragma unroll
        for (int off = 1; off < 16; off <<= 1) sum += __shfl_xor(sum, off, 16);
        p_s[l * 16 + m] = e / sum;
    }
    __syncthreads();

    for (int idx = tid; idx < 16 * 40; idx += 256) {
        int l = idx / 40, d = idx % 40;
        float acc = 0.f;
        #pragma unroll
        for (int m = 0; m < 16; ++m) acc += p_s[l * 16 + m] * v_s[m * 40 + d];
        ctx[(size_t)(l * 1024 + s) * 320 + hb + d] = (ushort_t)f2bf(acc);
    }
}

// ============================ fused panel kernels ===========================
// 32-row panels, 4 waves, wave grid 2x2. Panel LDS tiles use the SAME
// [row][64]-with-(row&7)-XOR layout as As -> identical fragment reads.

__device__ __forceinline__ void stage64(
    const ushort_t* __restrict__ src, int row0, int ldk, int k0,
    ushort_t* dst, int wave, int sr, int su)
{
    #pragma unroll
    for (int i = 0; i < 2; ++i) {
        const int c = i * 4 + wave;
        const int r = c * 8 + sr;
        const int gk = k0 + (su ^ (r & 7)) * 8;
        __builtin_amdgcn_global_load_lds(
            (gas_ptr)(src + (size_t)(row0 + r) * ldk + gk),
            (las_ptr)&dst[c * 512], 16, 0, 0);
    }
}
__device__ __forceinline__ void stage32(
    const ushort_t* __restrict__ src, int row0, int ldk, int k0,
    ushort_t* dst, int wave, int sr, int su)
{
    const int r = wave * 8 + sr;
    const int gk = k0 + (su ^ (r & 7)) * 8;
    __builtin_amdgcn_global_load_lds(
        (gas_ptr)(src + (size_t)(row0 + r) * ldk + gk),
        (las_ptr)&dst[wave * 512], 16, 0, 0);
}

// One 32x64 output phase step: A from global (32 rows), B tile 64 rows.
// wave grid 2x2: wr=row half (16 rows), wc=col half (32 cols).

// G2B: phase0 bb = fp2 . t1 (write out_bb fp32 + bbB bf16);
//      phase1 t2 = relu(fp1 . bb) (bb re-read via L2) -> LDS panel;
//      phase2 side = fp2 . t2 -> out_side + sideB.
__device__ void g2b_dev(
    int panel, const ushort_t* __restrict__ t1b,
    const ushort_t* __restrict__ fpW1b, const float* __restrict__ fpb1,
    const ushort_t* __restrict__ fpW2b, const float* __restrict__ fpb2,
    float* __restrict__ out_bb, ushort_t* __restrict__ bbB,
    float* __restrict__ out_side, ushort_t* __restrict__ sideB, char* smem)
{
    ushort_t* tpan = (ushort_t*)smem;       // 5 x [32][64] = 20 KB
    ushort_t* As   = tpan + 5 * 2048;       // 4 KB
    ushort_t* Bs   = As + 2048;             // 8 KB

    const int tid = threadIdx.x, wave = tid >> 6, lane = tid & 63;
    const int row0 = panel * 32;
    const int wr = wave >> 1, wc = wave & 1;
    const int sr = lane >> 3, su = lane & 7;

    // phase 0: bb = fp2 . t1 (no relu) -> global
    for (int nb = 0; nb < 5; ++nb) {
        f32x4 acc[2]; acc[0] = (f32x4)0.f; acc[1] = (f32x4)0.f;
        for (int k0 = 0; k0 < 320; k0 += 64) {
            stage32(t1b,   row0,    320, k0, As, wave, sr, su);
            stage64(fpW2b, nb * 64, 320, k0, Bs, wave, sr, su);
            __syncthreads();
            #pragma unroll
            for (int s = 0; s < 2; ++s) {
                bf16x8 a, b[2];
                {
                    const int r  = wr * 16 + (lane & 15);
                    const int lu = (s * 4 + (lane >> 4)) ^ (r & 7);
                    a = *reinterpret_cast<const bf16x8*>(&As[r * 64 + lu * 8]);
                }
                #pragma unroll
                for (int nf = 0; nf < 2; ++nf) {
                    const int r  = wc * 32 + nf * 16 + (lane & 15);
                    const int lu = (s * 4 + (lane >> 4)) ^ (r & 7);
                    b[nf] = *reinterpret_cast<const bf16x8*>(&Bs[r * 64 + lu * 8]);
                }
                #pragma unroll
                for (int nf = 0; nf < 2; ++nf)
                    acc[nf] = __builtin_amdgcn_mfma_f32_16x16x32_bf16(a, b[nf], acc[nf], 0, 0, 0);
            }
            __syncthreads();
        }
        #pragma unroll
        for (int nf = 0; nf < 2; ++nf) {
            const int gn = nb * 64 + wc * 32 + nf * 16 + (lane & 15);
            const float bv = fpb2[gn];
            #pragma unroll
            for (int i = 0; i < 4; ++i) {
                const int gm = row0 + wr * 16 + (lane >> 4) * 4 + i;
                float v = acc[nf][i] + bv;
                out_bb[(size_t)gm * 320 + gn] = v;
                bbB[(size_t)gm * 320 + gn] = (ushort_t)f2bf(v);
            }
        }
    }
    __syncthreads();   // drain stores (barrier implies vmcnt(0)) before re-read

    // phase 1: t2 = relu(fp1 . bb) -> LDS panel
    for (int nb = 0; nb < 5; ++nb) {
        f32x4 acc[2]; acc[0] = (f32x4)0.f; acc[1] = (f32x4)0.f;
        for (int k0 = 0; k0 < 320; k0 += 64) {
            stage32(bbB,   row0,    320, k0, As, wave, sr, su);
            stage64(fpW1b, nb * 64, 320, k0, Bs, wave, sr, su);
            __syncthreads();
            #pragma unroll
            for (int s = 0; s < 2; ++s) {
                bf16x8 a, b[2];
                {
                    const int r  = wr * 16 + (lane & 15);
                    const int lu = (s * 4 + (lane >> 4)) ^ (r & 7);
                    a = *reinterpret_cast<const bf16x8*>(&As[r * 64 + lu * 8]);
                }
                #pragma unroll
                for (int nf = 0; nf < 2; ++nf) {
                    const int r  = wc * 32 + nf * 16 + (lane & 15);
                    const int lu = (s * 4 + (lane >> 4)) ^ (r & 7);
                    b[nf] = *reinterpret_cast<const bf16x8*>(&Bs[r * 64 + lu * 8]);
                }
                #pragma unroll
                for (int nf = 0; nf < 2; ++nf)
                    acc[nf] = __builtin_amdgcn_mfma_f32_16x16x32_bf16(a, b[nf], acc[nf], 0, 0, 0);
            }
            __syncthreads();
        }
        #pragma unroll
        for (int nf = 0; nf < 2; ++nf) {
            const int col = wc * 32 + nf * 16 + (lane & 15);
            const float bv = fpb1[nb * 64 + col];
            #pragma unroll
            for (int i = 0; i < 4; ++i) {
                const int row = wr * 16 + (lane >> 4) * 4 + i;
                float v = fmaxf(acc[nf][i] + bv, 0.f);
                const int u = col >> 3;
                tpan[nb * 2048 + row * 64 + ((u ^ (row & 7)) * 8) + (col & 7)]
                    = (ushort_t)f2bf(v);
            }
        }
        __syncthreads();
    }

    // phase 2: side = fp2 . t2
    for (int nb = 0; nb < 5; ++nb) {
        f32x4 acc[2]; acc[0] = (f32x4)0.f; acc[1] = (f32x4)0.f;
        for (int kt = 0; kt < 5; ++kt) {
            stage64(fpW2b, nb * 64, 320, kt * 64, Bs, wave, sr, su);
            __syncthreads();
            #pragma unroll
            for (int s = 0; s < 2; ++s) {
                bf16x8 a, b[2];
                {
                    const int r  = wr * 16 + (lane & 15);
                    const int lu = (s * 4 + (lane >> 4)) ^ (r & 7);
                    a = *reinterpret_cast<const bf16x8*>(&tpan[kt * 2048 + r * 64 + lu * 8]);
                }
                #pragma unroll
                for (int nf = 0; nf < 2; ++nf) {
                    const int r  = wc * 32 + nf * 16 + (lane & 15);
                    const int lu = (s * 4 + (lane >> 4)) ^ (r & 7);
                    b[nf] = *reinterpret_cast<const bf16x8*>(&Bs[r * 64 + lu * 8]);
                }
                #pragma unroll
                for (int nf = 0; nf < 2; ++nf)
                    acc[nf] = __builtin_amdgcn_mfma_f32_16x16x32_bf16(a, b[nf], acc[nf], 0, 0, 0);
            }
            __syncthreads();
        }
        #pragma unroll
        for (int nf = 0; nf < 2; ++nf) {
            const int gn = nb * 64 + wc * 32 + nf * 16 + (lane & 15);
            const float bv = fpb2[gn];
            #pragma unroll
            for (int i = 0; i < 4; ++i) {
                const int gm = row0 + wr * 16 + (lane >> 4) * 4 + i;
                float v = acc[nf][i] + bv;
                out_side[(size_t)gm * 320 + gn] = v;
                sideB[(size_t)gm * 320 + gn] = (ushort_t)f2bf(v);
            }
        }
    }
}

// fusedC32: t3 = relu(pW1 . [bb|side]) (LDS panel, K=640) ;
//           c2 = relu(pW2 . t3) in regs ; refined = c2 . pW3 + pb3 (verified r10/r11)
__device__ void fusedC32_dev(
    int panel, const ushort_t* __restrict__ bbB, const ushort_t* __restrict__ sideB,
    const ushort_t* __restrict__ pW1b, const float* __restrict__ pb1,
    const ushort_t* __restrict__ pW2b, const float* __restrict__ pb2,
    const float* __restrict__ pW3, const float* __restrict__ pb3,
    float* __restrict__ out_ref, char* smem)
{
    ushort_t* tpan = (ushort_t*)smem;       // 20 KB
    ushort_t* As   = tpan + 5 * 2048;       // 4 KB
    ushort_t* Bs   = As + 2048;             // 8 KB
    float*    pSum = (float*)(Bs + 4096);   // [2][32][3]

    const int tid = threadIdx.x, wave = tid >> 6, lane = tid & 63;
    const int row0 = panel * 32;
    const int wr = wave >> 1, wc = wave & 1;
    const int sr = lane >> 3, su = lane & 7;

    for (int nb = 0; nb < 5; ++nb) {
        f32x4 acc[2]; acc[0] = (f32x4)0.f; acc[1] = (f32x4)0.f;
        for (int k0 = 0; k0 < 640; k0 += 64) {
            {
                const int r = wave * 8 + sr;
                const int gk = k0 + (su ^ (r & 7)) * 8;
                const ushort_t* src = (gk < 320)
                    ? bbB   + (size_t)(row0 + r) * 320 + gk
                    : sideB + (size_t)(row0 + r) * 320 + (gk - 320);
                __builtin_amdgcn_global_load_lds((gas_ptr)src, (las_ptr)&As[wave * 512], 16, 0, 0);
            }
            stage64(pW1b, nb * 64, 640, k0, Bs, wave, sr, su);
            __syncthreads();
            #pragma unroll
            for (int s = 0; s < 2; ++s) {
                bf16x8 a, b[2];
                {
                    const int r  = wr * 16 + (lane & 15);
                    const int lu = (s * 4 + (lane >> 4)) ^ (r & 7);
                    a = *reinterpret_cast<const bf16x8*>(&As[r * 64 + lu * 8]);
                }
                #pragma unroll
                for (int nf = 0; nf < 2; ++nf) {
                    const int r  = wc * 32 + nf * 16 + (lane & 15);
                    const int lu = (s * 4 + (lane >> 4)) ^ (r & 7);
                    b[nf] = *reinterpret_cast<const bf16x8*>(&Bs[r * 64 + lu * 8]);
                }
                #pragma unroll
                for (int nf = 0; nf < 2; ++nf)
                    acc[nf] = __builtin_amdgcn_mfma_f32_16x16x32_bf16(a, b[nf], acc[nf], 0, 0, 0);
            }
            __syncthreads();
        }
        #pragma unroll
        for (int nf = 0; nf < 2; ++nf) {
            const int col = wc * 32 + nf * 16 + (lane & 15);
            const float bv = pb1[nb * 64 + col];
            #pragma unroll
            for (int i = 0; i < 4; ++i) {
                const int row = wr * 16 + (lane >> 4) * 4 + i;
                float v = fmaxf(acc[nf][i] + bv, 0.f);
                const int u = col >> 3;
                tpan[nb * 2048 + row * 64 + ((u ^ (row & 7)) * 8) + (col & 7)]
                    = (ushort_t)f2bf(v);
            }
        }
        __syncthreads();
    }

    float part[4][3];
    #pragma unroll
    for (int i = 0; i < 4; ++i) { part[i][0] = part[i][1] = part[i][2] = 0.f; }

    for (int ct = 0; ct < 5; ++ct) {
        f32x4 acc = (f32x4)0.f;
        for (int kt = 0; kt < 5; ++kt) {
            stage32(pW2b, ct * 32, 320, kt * 64, Bs, wave, sr, su);
            __syncthreads();
            #pragma unroll
            for (int s = 0; s < 2; ++s) {
                bf16x8 a, b;
                {
                    const int r  = wr * 16 + (lane & 15);
                    const int lu = (s * 4 + (lane >> 4)) ^ (r & 7);
                    a = *reinterpret_cast<const bf16x8*>(&tpan[kt * 2048 + r * 64 + lu * 8]);
                }
                {
                    const int r  = wc * 16 + (lane & 15);
                    const int lu = (s * 4 + (lane >> 4)) ^ (r & 7);
                    b = *reinterpret_cast<const bf16x8*>(&Bs[r * 64 + lu * 8]);
                }
                acc = __builtin_amdgcn_mfma_f32_16x16x32_bf16(a, b, acc, 0, 0, 0);
            }
            __syncthreads();
        }
        const int col = ct * 32 + wc * 16 + (lane & 15);
        const float bv = pb2[col];
        #pragma unroll
        for (int i = 0; i < 4; ++i) {
            float v = fmaxf(acc[i] + bv, 0.f);
            #pragma unroll
            for (int n = 0; n < 3; ++n)
                part[i][n] += v * pW3[n * 160 + col];
        }
    }
    #pragma unroll
    for (int off = 8; off; off >>= 1)
        #pragma unroll
        for (int i = 0; i < 4; ++i)
            #pragma unroll
            for (int n = 0; n < 3; ++n)
                part[i][n] += __shfl_xor(part[i][n], off, 16);
    if ((lane & 15) == 0) {
        #pragma unroll
        for (int i = 0; i < 4; ++i) {
            const int row = wr * 16 + (lane >> 4) * 4 + i;
            #pragma unroll
            for (int n = 0; n < 3; ++n)
                pSum[(wc * 32 + row) * 3 + n] = part[i][n];
        }
    }
    __syncthreads();
    if (tid < 96) {
        const int row = tid / 3, n = tid % 3;
        out_ref[(size_t)(row0 + row) * 3 + n] =
            pSum[row * 3 + n] + pSum[(32 + row) * 3 + n] + pb3[n];
    }
}

// fusedD32: phase0 ao = Wo . ctx + bo -> LDS panel (no global round trip);
//           phase1 c1 = relu(mW1 . ao), prob = c1 . mW2 + mb2, contact rows.
__device__ void fusedD32_dev(
    int panel, const ushort_t* __restrict__ ctxb,
    const ushort_t* __restrict__ Wob, const float* __restrict__ bo,
    const ushort_t* __restrict__ mW1b, const float* __restrict__ mb1,
    const float* __restrict__ mW2, const float* __restrict__ mb2,
    float* __restrict__ out_cm, char* smem)
{
    ushort_t* tpan = (ushort_t*)smem;       // ao panel, 5 x [32][64] = 20 KB
    ushort_t* As   = tpan + 5 * 2048;       // 4 KB
    ushort_t* Bs   = As + 2048;             // 8 KB
    float*    pSum = (float*)(Bs + 4096);   // [2][32]
    float*    probs= pSum + 64;             // [32]

    const int tid = threadIdx.x, wave = tid >> 6, lane = tid & 63;
    const int row0 = panel * 32;
    const int wr = wave >> 1, wc = wave & 1;
    const int sr = lane >> 3, su = lane & 7;

    // phase 0: ao = Wo . ctx + bo -> tpan (bf16, swizzled)
    for (int nb = 0; nb < 5; ++nb) {
        f32x4 acc[2]; acc[0] = (f32x4)0.f; acc[1] = (f32x4)0.f;
        for (int k0 = 0; k0 < 320; k0 += 64) {
            stage32(ctxb, row0,    320, k0, As, wave, sr, su);
            stage64(Wob,  nb * 64, 320, k0, Bs, wave, sr, su);
            __syncthreads();
            #pragma unroll
            for (int s = 0; s < 2; ++s) {
                bf16x8 a, b[2];
                {
                    const int r  = wr * 16 + (lane & 15);
                    const int lu = (s * 4 + (lane >> 4)) ^ (r & 7);
                    a = *reinterpret_cast<const bf16x8*>(&As[r * 64 + lu * 8]);
                }
                #pragma unroll
                for (int nf = 0; nf < 2; ++nf) {
                    const int r  = wc * 32 + nf * 16 + (lane & 15);
                    const int lu = (s * 4 + (lane >> 4)) ^ (r & 7);
                    b[nf] = *reinterpret_cast<const bf16x8*>(&Bs[r * 64 + lu * 8]);
                }
                #pragma unroll
                for (int nf = 0; nf < 2; ++nf)
                    acc[nf] = __builtin_amdgcn_mfma_f32_16x16x32_bf16(a, b[nf], acc[nf], 0, 0, 0);
            }
            __syncthreads();
        }
        #pragma unroll
        for (int nf = 0; nf < 2; ++nf) {
            const int col = wc * 32 + nf * 16 + (lane & 15);
            const float bv = bo[nb * 64 + col];
            #pragma unroll
            for (int i = 0; i < 4; ++i) {
                const int row = wr * 16 + (lane >> 4) * 4 + i;
                float v = acc[nf][i] + bv;
                const int u = col >> 3;
                tpan[nb * 2048 + row * 64 + ((u ^ (row & 7)) * 8) + (col & 7)]
                    = (ushort_t)f2bf(v);
            }
        }
        __syncthreads();
    }

    // phase 1: c1 = relu(mW1 . ao); prob partials via mW2
    float part[4] = {0.f, 0.f, 0.f, 0.f};
    for (int ct = 0; ct < 5; ++ct) {
        f32x4 acc = (f32x4)0.f;
        for (int kt = 0; kt < 5; ++kt) {
            stage32(mW1b, ct * 32, 320, kt * 64, Bs, wave, sr, su);
            __syncthreads();
            #pragma unroll
            for (int s = 0; s < 2; ++s) {
                bf16x8 a, b;
                {
                    const int r  = wr * 16 + (lane & 15);
                    const int lu = (s * 4 + (lane >> 4)) ^ (r & 7);
                    a = *reinterpret_cast<const bf16x8*>(&tpan[kt * 2048 + r * 64 + lu * 8]);
                }
                {
                    const int r  = wc * 16 + (lane & 15);
                    const int lu = (s * 4 + (lane >> 4)) ^ (r & 7);
                    b = *reinterpret_cast<const bf16x8*>(&Bs[r * 64 + lu * 8]);
                }
                acc = __builtin_amdgcn_mfma_f32_16x16x32_bf16(a, b, acc, 0, 0, 0);
            }
            __syncthreads();
        }
        const int col = ct * 32 + wc * 16 + (lane & 15);
        const float bv = mb1[col];
        const float w  = mW2[col];
        #pragma unroll
        for (int i = 0; i < 4; ++i)
            part[i] += fmaxf(acc[i] + bv, 0.f) * w;
    }
    #pragma unroll
    for (int off = 8; off; off >>= 1)
        #pragma unroll
        for (int i = 0; i < 4; ++i)
            part[i] += __shfl_xor(part[i], off, 16);
    if ((lane & 15) == 0) {
        #pragma unroll
        for (int i = 0; i < 4; ++i) {
            const int row = wr * 16 + (lane >> 4) * 4 + i;
            pSum[wc * 32 + row] = part[i];
        }
    }
    __syncthreads();
    if (tid < 32) probs[tid] = pSum[tid] + pSum[32 + tid] + mb2[0];
    __syncthreads();

    for (int r = 0; r < 32; ++r) {
        const float p = probs[r];
        reinterpret_cast<float4*>(out_cm + (size_t)(row0 + r) * 1024)[tid] =
            make_float4(p, p, p, p);
    }
}

// ================================ kernels ===================================

struct ConvDesc { const float* src; ushort_t* dst; };
struct ConvPack { ConvDesc d[5]; int start[6]; };

__device__ __forceinline__ void conv_unit(const ConvPack& p, int u, int tid)
{
    int i = 0;
    #pragma unroll
    for (int t = 0; t < 5; ++t) if (u >= p.start[t + 1]) i = t + 1;
    const int idx = ((u - p.start[i]) * 256 + tid) * 4;
    float4 v = *reinterpret_cast<const float4*>(&p.d[i].src[idx]);
    unsigned int lo = f2bf(v.x) | (f2bf(v.y) << 16);
    unsigned int hi = f2bf(v.z) | (f2bf(v.w) << 16);
    *reinterpret_cast<uint2*>(&p.d[i].dst[idx]) = make_uint2(lo, hi);
}

__global__ __launch_bounds__(256) void conv_k(ConvPack p)
{
    conv_unit(p, blockIdx.x, threadIdx.x);
}

// G1: x -> [fp1(relu) | q | k | v], N=1280, XCD-aware panel map (verified r11).
// Blocks [2560, 2560+500): convert the 5 weight matrices later stages need.
__global__ __launch_bounds__(256) void k_g1(
    const ushort_t* __restrict__ xb, const ushort_t* __restrict__ Wcat,
    const float* __restrict__ fpb1, const float* __restrict__ bq,
    const float* __restrict__ bk, const float* __restrict__ bvv,
    ushort_t* __restrict__ t1b, ushort_t* __restrict__ qkvb, ConvPack cp)
{
    __shared__ __align__(16) char smem[24 * 1024];
    const int bid = blockIdx.x;
    if (bid >= 2560) { conv_unit(cp, bid - 2560, threadIdx.x); return; }

    const int xcd = bid & 7;
    const int i0  = bid >> 3;            // 0..319
    const int ty  = xcd * 16 + i0 / 20;  // 0..127
    const int tx  = i0 % 20;

    f32x4 acc[4][2];
    #pragma unroll
    for (int i = 0; i < 4; ++i) { acc[i][0] = (f32x4)0.f; acc[i][1] = (f32x4)0.f; }
    gemm_core<64>(tx, ty, xb, xb, 320, 320, Wcat, smem, acc);

    const int tid = threadIdx.x, wave = tid >> 6, lane = tid & 63;
    const int wr = wave >> 1, wc = wave & 1;
    #pragma unroll
    for (int nf = 0; nf < 2; ++nf) {
        const int gn = tx * 64 + wc * 32 + nf * 16 + (lane & 15);
        float bv;
        if      (gn < 320) bv = fpb1[gn];
        else if (gn < 640) bv = bq[gn - 320];
        else if (gn < 960) bv = bk[gn - 640];
        else               bv = bvv[gn - 960];
        #pragma unroll
        for (int mf = 0; mf < 4; ++mf) {
            #pragma unroll
            for (int i = 0; i < 4; ++i) {
                const int gm = ty * 128 + wr * 64 + mf * 16 + (lane >> 4) * 4 + i;
                float v = acc[mf][nf][i] + bv;
                if (gn < 320) t1b [(size_t)gm * 320 + gn] = (ushort_t)f2bf(fmaxf(v, 0.f));
                else          qkvb[(size_t)gm * 960 + gn - 320] = (ushort_t)f2bf(v);
            }
        }
    }
}

// L2: [0,512) G2B (bb->t2->side), [512,8704) attention
__global__ __launch_bounds__(256) void k_l2(
    const ushort_t* __restrict__ t1b,
    const ushort_t* __restrict__ fpW1b, const float* __restrict__ fpb1,
    const ushort_t* __restrict__ fpW2b, const float* __restrict__ fpb2,
    float* __restrict__ out_bb, ushort_t* __restrict__ bbB,
    float* __restrict__ out_side, ushort_t* __restrict__ sideB,
    const ushort_t* __restrict__ qkvb, ushort_t* __restrict__ ctxb)
{
    __shared__ __align__(16) char smem[33 * 1024];
    const int bid = blockIdx.x;
    if (bid < 512) g2b_dev(bid, t1b, fpW1b, fpb1, fpW2b, fpb2,
                           out_bb, bbB, out_side, sideB, smem);
    else           attn_dev(bid - 512, qkvb, ctxb, smem);
}

// L3: [0,512) fusedC32 (refined), [512,1024) fusedD32 (contact)
__global__ __launch_bounds__(256) void k_l3(
    const ushort_t* __restrict__ bbB, const ushort_t* __restrict__ sideB,
    const ushort_t* __restrict__ pW1b, const float* __restrict__ pb1,
    const ushort_t* __restrict__ pW2b, const float* __restrict__ pb2,
    const float* __restrict__ pW3, const float* __restrict__ pb3,
    float* __restrict__ out_ref,
    const ushort_t* __restrict__ ctxb,
    const ushort_t* __restrict__ Wob, const float* __restrict__ bo,
    const ushort_t* __restrict__ mW1b, const float* __restrict__ mb1,
    const float* __restrict__ mW2, const float* __restrict__ mb2,
    float* __restrict__ out_cm)
{
    __shared__ __align__(16) char smem[34 * 1024];
    const int bid = blockIdx.x;
    if (bid < 512) fusedC32_dev(bid, bbB, sideB, pW1b, pb1, pW2b, pb2, pW3, pb3, out_ref, smem);
    else           fusedD32_dev(bid - 512, ctxb, Wob, bo, mW1b, mb1, mW2, mb2, out_cm, smem);
}

extern "C" void kernel_launch(void* const* d_in, const int* in_sizes, int n_in,
                              void* d_out, int out_size, void* d_ws, size_t ws_size,
                              hipStream_t stream)
{
    const float* x    = (const float*)d_in[0];
    const float* fpW1 = (const float*)d_in[1];
    const float* fpb1 = (const float*)d_in[2];
    const float* fpW2 = (const float*)d_in[3];
    const float* fpb2 = (const float*)d_in[4];
    const float* Wq   = (const float*)d_in[5];
    const float* bq   = (const float*)d_in[6];
    const float* Wk   = (const float*)d_in[7];
    const float* bk   = (const float*)d_in[8];
    const float* Wv   = (const float*)d_in[9];
    const float* bv   = (const float*)d_in[10];
    const float* Wo   = (const float*)d_in[11];
    const float* bo   = (const float*)d_in[12];
    const float* mW1  = (const float*)d_in[13];
    const float* mb1  = (const float*)d_in[14];
    const float* mW2  = (const float*)d_in[15];
    const float* mb2  = (const float*)d_in[16];
    const float* pW1  = (const float*)d_in[17];
    const float* pb1  = (const float*)d_in[18];
    const float* pW2  = (const float*)d_in[19];
    const float* pb2  = (const float*)d_in[20];
    const float* pW3  = (const float*)d_in[21];
    const float* pb3  = (const float*)d_in[22];

    float* out      = (float*)d_out;
    float* out_bb   = out;
    float* out_side = out + 5242880;
    float* out_cm   = out + 2 * 5242880;
    float* out_ref  = out + 2 * 5242880 + 16777216;

    ushort_t* ws = (ushort_t*)d_ws;
    const size_t BUF = 5242880;
    ushort_t* xb    = ws;              // x bf16; later ctx
    ushort_t* t1b   = ws + 1 * BUF;    // fp1(x) relu
    ushort_t* bbB   = ws + 2 * BUF;
    ushort_t* sideB = ws + 3 * BUF;
    ushort_t* qkvb  = ws + 4 * BUF;    // [M,960] spans 3 BUFs
    ushort_t* wb    = ws + 7 * BUF;
    ushort_t* fpW1b = wb;              // Wcat = [fpW1|Wq|Wk|Wv] contiguous
    ushort_t* Wqb   = wb + 102400;
    ushort_t* Wkb   = wb + 204800;
    ushort_t* Wvb   = wb + 307200;
    ushort_t* fpW2b = wb + 409600;
    ushort_t* Wob   = wb + 512000;
    ushort_t* mW1b  = wb + 614400;
    ushort_t* pW1b  = wb + 665600;
    ushort_t* pW2b  = wb + 870400;

    ushort_t* ctxb = xb;               // alias (x dead after L1)

    dim3 blk(256);

    // L0: convert x + Wcat (what G1 needs)
    ConvPack cp0;
    {
        const float* s[5] = {x, fpW1, Wq, Wk, Wv};
        ushort_t*    d[5] = {xb, fpW1b, Wqb, Wkb, Wvb};
        const int    n[5] = {5120, 100, 100, 100, 100};
        int a = 0;
        for (int i = 0; i < 5; ++i) { cp0.d[i] = {s[i], d[i]}; cp0.start[i] = a; a += n[i]; }
        cp0.start[5] = a;   // 5520
    }
    conv_k<<<dim3(5520), blk, 0, stream>>>(cp0);

    // L1: G1 (2560, XCD-aware) || convert remaining 5 weight matrices (500)
    ConvPack cp1;
    {
        const float* s[5] = {fpW2, Wo, mW1, pW1, pW2};
        ushort_t*    d[5] = {fpW2b, Wob, mW1b, pW1b, pW2b};
        const int    n[5] = {100, 100, 50, 200, 50};
        int a = 0;
        for (int i = 0; i < 5; ++i) { cp1.d[i] = {s[i], d[i]}; cp1.start[i] = a; a += n[i]; }
        cp1.start[5] = a;   // 500
    }
    k_g1<<<dim3(2560 + 500), blk, 0, stream>>>(xb, wb, fpb1, bq, bk, bv, t1b, qkvb, cp1);

    // L2: G2B (bb->t2->side, 512) || attention (8192)
    k_l2<<<dim3(8704), blk, 0, stream>>>(t1b, fpW1b, fpb1, fpW2b, fpb2,
                                         out_bb, bbB, out_side, sideB, qkvb, ctxb);
    // L3: fusedC32 (refined, 512) || fusedD32 (contact, 512)
    k_l3<<<dim3(1024), blk, 0, stream>>>(bbB, sideB, pW1b, pb1, pW2b, pb2, pW3, pb3,
                                         out_ref, ctxb, Wob, bo, mW1b, mb1, mW2, mb2, out_cm);
}

// Round 13
// 132.582 us; speedup vs baseline: 1.2689x; 1.0004x over previous
//
#include <hip/hip_runtime.h>
#include <math.h>

// B=16, S=1024, E=320, H=8, DH=40 -> M = 16384 rows.
// bf16 MFMA everywhere. 4 launches:
//   L0 conv(x+Wcat) -> L1 {G1 || conv-rest} ->
//   L2 {G2B(bb->t2->side, 512) || attn(8192)} ->
//   L3 {fusedC32(refined, 512) || fusedD32(contact, 512)}
// r13: XCD-aligned panel permutation p=(bid&7)*64+(bid>>3) for G2B/C32/D32 so
// consumers run on the XCD that wrote their rows (r7/r11: FETCH 93->24 MB);
// conversions vectorized to 8 floats/thread.

#define M_ROWS 16384

typedef float f32x4 __attribute__((ext_vector_type(4)));
typedef __bf16 bf16x8 __attribute__((ext_vector_type(8)));
typedef unsigned short ushort_t;

typedef const __attribute__((address_space(1))) void* gas_ptr;
typedef __attribute__((address_space(3))) void* las_ptr;

__device__ __forceinline__ unsigned int f2bf(float f) {
    union { float f; unsigned int u; } v; v.f = f;
    unsigned int u = v.u + 0x7FFFu + ((v.u >> 16) & 1u);   // RNE
    return u >> 16;
}
__device__ __forceinline__ float bf2f(ushort_t s) {
    union { unsigned int u; float f; } v; v.u = ((unsigned int)s) << 16;
    return v.f;
}

// ---------------------------------------------------------------------------
// GEMM core (verified r2/r3): BM=128, BK=64, 4 waves, mfma 16x16x32 bf16.
// LDS row-major [rows][64] bf16, unit-XOR swizzle by (row&7); global_load_lds
// dest linear, SOURCE column pre-swizzled (both-sides rule #21).
// ---------------------------------------------------------------------------
template<int BN>
__device__ __forceinline__ void gemm_core(
    int tx, int ty,
    const ushort_t* __restrict__ X1, const ushort_t* __restrict__ X2,
    int ksplit, int K, const ushort_t* __restrict__ W,
    char* smem, f32x4 (*acc)[2])
{
    constexpr int BM = 128, BK = 64;
    constexpr int WROWS = (BN == 64) ? 2 : 4;
    constexpr int WCOLS = 4 / WROWS;
    constexpr int WM = BM / WROWS;
    constexpr int WN = BN / WCOLS;   // 32
    constexpr int MF = WM / 16;
    constexpr int NF = WN / 16;      // 2

    ushort_t* As = (ushort_t*)smem;
    ushort_t* Bs = As + BM * BK;

    const int tid  = threadIdx.x;
    const int wave = tid >> 6;
    const int lane = tid & 63;
    const int m0 = ty * BM;
    const int n0 = tx * BN;
    const int wr = wave / WCOLS;
    const int wc = wave % WCOLS;
    const int sr = lane >> 3;
    const int su = lane & 7;

    for (int k0 = 0; k0 < K; k0 += BK) {
        #pragma unroll
        for (int i = 0; i < (BM * BK * 2) / 4096; ++i) {
            const int c = i * 4 + wave;
            const int r = c * 8 + sr;
            const int gk = k0 + (su ^ (r & 7)) * 8;
            const ushort_t* src;
            if (gk < ksplit) src = X1 + (size_t)(m0 + r) * ksplit + gk;
            else             src = X2 + (size_t)(m0 + r) * (K - ksplit) + (gk - ksplit);
            __builtin_amdgcn_global_load_lds((gas_ptr)src, (las_ptr)&As[c * 512], 16, 0, 0);
        }
        #pragma unroll
        for (int i = 0; i < (BN * BK * 2) / 4096; ++i) {
            const int c = i * 4 + wave;
            const int r = c * 8 + sr;
            const int gk = k0 + (su ^ (r & 7)) * 8;
            const ushort_t* src = W + (size_t)(n0 + r) * K + gk;
            __builtin_amdgcn_global_load_lds((gas_ptr)src, (las_ptr)&Bs[c * 512], 16, 0, 0);
        }
        __syncthreads();

        #pragma unroll
        for (int s = 0; s < 2; ++s) {
            bf16x8 a[MF], b[NF];
            #pragma unroll
            for (int mf = 0; mf < MF; ++mf) {
                const int r  = wr * WM + mf * 16 + (lane & 15);
                const int lu = (s * 4 + (lane >> 4)) ^ (r & 7);
                a[mf] = *reinterpret_cast<const bf16x8*>(&As[r * 64 + lu * 8]);
            }
            #pragma unroll
            for (int nf = 0; nf < NF; ++nf) {
                const int r  = wc * WN + nf * 16 + (lane & 15);
                const int lu = (s * 4 + (lane >> 4)) ^ (r & 7);
                b[nf] = *reinterpret_cast<const bf16x8*>(&Bs[r * 64 + lu * 8]);
            }
            #pragma unroll
            for (int mf = 0; mf < MF; ++mf)
                #pragma unroll
                for (int nf = 0; nf < NF; ++nf)
                    acc[mf][nf] = __builtin_amdgcn_mfma_f32_16x16x32_bf16(
                        a[mf], b[nf], acc[mf][nf], 0, 0, 0);
        }
        __syncthreads();
    }
}

// --- attention over batch axis (per (s,h): 16x16 scores over DH=40) ---------
__device__ __forceinline__ void attn_dev(
    int ab, const ushort_t* __restrict__ qkv, ushort_t* __restrict__ ctx, char* smem)
{
    float* q_s = (float*)smem;            // [16][40]
    float* k_s = q_s + 16 * 40;
    float* v_s = k_s + 16 * 40;
    float* p_s = v_s + 16 * 40;           // [16][16]

    const int s   = ab >> 3;
    const int h   = ab & 7;
    const int tid = threadIdx.x;
    const int hb  = h * 40;

    if (tid < 240) {                      // 3 mats x 16 rows x 5 chunks of 8
        const int mat = tid / 80;
        const int rem = tid % 80;
        const int l = rem / 5, c8 = rem % 5;
        const size_t g = (size_t)(l * 1024 + s) * 960 + mat * 320 + hb + c8 * 8;
        bf16x8 vv = *reinterpret_cast<const bf16x8*>(&qkv[g]);
        const ushort_t* pu = reinterpret_cast<const ushort_t*>(&vv);
        float* dst = (mat == 0 ? q_s : mat == 1 ? k_s : v_s) + l * 40 + c8 * 8;
        #pragma unroll
        for (int j = 0; j < 8; ++j) dst[j] = bf2f(pu[j]);
    }
    __syncthreads();

    {
        const int l = tid >> 4, m = tid & 15;
        float sc = 0.f;
        #pragma unroll
        for (int d = 0; d < 40; ++d) sc += q_s[l * 40 + d] * k_s[m * 40 + d];
        sc *= 0.15811388300841897f;   // 1/sqrt(40)
        float mx = sc;
        #pragma unroll
        for (int off = 1; off < 16; off <<= 1) mx = fmaxf(mx, __shfl_xor(mx, off, 16));
        float e = expf(sc - mx);
        float sum = e;
        #pragma unroll
        for (int off = 1; off < 16; off <<= 1) sum += __shfl_xor(sum, off, 16);
        p_s[l * 16 + m] = e / sum;
    }
    __syncthreads();

    for (int idx = tid; idx < 16 * 40; idx += 256) {
        int l = idx / 40, d = idx % 40;
        float acc = 0.f;
        #pragma unroll
        for (int m = 0; m < 16; ++m) acc += p_s[l * 16 + m] * v_s[m * 40 + d];
        ctx[(size_t)(l * 1024 + s) * 320 + hb + d] = (ushort_t)f2bf(acc);
    }
}

// ============================ fused panel kernels ===========================
// 32-row panels, 4 waves, wave grid 2x2. Panel LDS tiles use the SAME
// [row][64]-with-(row&7)-XOR layout as As -> identical fragment reads.

__device__ __forceinline__ void stage64(
    const ushort_t* __restrict__ src, int row0, int ldk, int k0,
    ushort_t* dst, int wave, int sr, int su)
{
    #pragma unroll
    for (int i = 0; i < 2; ++i) {
        const int c = i * 4 + wave;
        const int r = c * 8 + sr;
        const int gk = k0 + (su ^ (r & 7)) * 8;
        __builtin_amdgcn_global_load_lds(
            (gas_ptr)(src + (size_t)(row0 + r) * ldk + gk),
            (las_ptr)&dst[c * 512], 16, 0, 0);
    }
}
__device__ __forceinline__ void stage32(
    const ushort_t* __restrict__ src, int row0, int ldk, int k0,
    ushort_t* dst, int wave, int sr, int su)
{
    const int r = wave * 8 + sr;
    const int gk = k0 + (su ^ (r & 7)) * 8;
    __builtin_amdgcn_global_load_lds(
        (gas_ptr)(src + (size_t)(row0 + r) * ldk + gk),
        (las_ptr)&dst[wave * 512], 16, 0, 0);
}

// G2B: phase0 bb = fp2 . t1 (write out_bb fp32 + bbB bf16);
//      phase1 t2 = relu(fp1 . bb) (bb re-read via same-XCD L2) -> LDS panel;
//      phase2 side = fp2 . t2 -> out_side + sideB.  (verified r12)
__device__ void g2b_dev(
    int panel, const ushort_t* __restrict__ t1b,
    const ushort_t* __restrict__ fpW1b, const float* __restrict__ fpb1,
    const ushort_t* __restrict__ fpW2b, const float* __restrict__ fpb2,
    float* __restrict__ out_bb, ushort_t* __restrict__ bbB,
    float* __restrict__ out_side, ushort_t* __restrict__ sideB, char* smem)
{
    ushort_t* tpan = (ushort_t*)smem;       // 5 x [32][64] = 20 KB
    ushort_t* As   = tpan + 5 * 2048;       // 4 KB
    ushort_t* Bs   = As + 2048;             // 8 KB

    const int tid = threadIdx.x, wave = tid >> 6, lane = tid & 63;
    const int row0 = panel * 32;
    const int wr = wave >> 1, wc = wave & 1;
    const int sr = lane >> 3, su = lane & 7;

    // phase 0: bb = fp2 . t1 (no relu) -> global
    for (int nb = 0; nb < 5; ++nb) {
        f32x4 acc[2]; acc[0] = (f32x4)0.f; acc[1] = (f32x4)0.f;
        for (int k0 = 0; k0 < 320; k0 += 64) {
            stage32(t1b,   row0,    320, k0, As, wave, sr, su);
            stage64(fpW2b, nb * 64, 320, k0, Bs, wave, sr, su);
            __syncthreads();
            #pragma unroll
            for (int s = 0; s < 2; ++s) {
                bf16x8 a, b[2];
                {
                    const int r  = wr * 16 + (lane & 15);
                    const int lu = (s * 4 + (lane >> 4)) ^ (r & 7);
                    a = *reinterpret_cast<const bf16x8*>(&As[r * 64 + lu * 8]);
                }
                #pragma unroll
                for (int nf = 0; nf < 2; ++nf) {
                    const int r  = wc * 32 + nf * 16 + (lane & 15);
                    const int lu = (s * 4 + (lane >> 4)) ^ (r & 7);
                    b[nf] = *reinterpret_cast<const bf16x8*>(&Bs[r * 64 + lu * 8]);
                }
                #pragma unroll
                for (int nf = 0; nf < 2; ++nf)
                    acc[nf] = __builtin_amdgcn_mfma_f32_16x16x32_bf16(a, b[nf], acc[nf], 0, 0, 0);
            }
            __syncthreads();
        }
        #pragma unroll
        for (int nf = 0; nf < 2; ++nf) {
            const int gn = nb * 64 + wc * 32 + nf * 16 + (lane & 15);
            const float bv = fpb2[gn];
            #pragma unroll
            for (int i = 0; i < 4; ++i) {
                const int gm = row0 + wr * 16 + (lane >> 4) * 4 + i;
                float v = acc[nf][i] + bv;
                out_bb[(size_t)gm * 320 + gn] = v;
                bbB[(size_t)gm * 320 + gn] = (ushort_t)f2bf(v);
            }
        }
    }
    __syncthreads();   // barrier drains this block's stores before re-read

    // phase 1: t2 = relu(fp1 . bb) -> LDS panel
    for (int nb = 0; nb < 5; ++nb) {
        f32x4 acc[2]; acc[0] = (f32x4)0.f; acc[1] = (f32x4)0.f;
        for (int k0 = 0; k0 < 320; k0 += 64) {
            stage32(bbB,   row0,    320, k0, As, wave, sr, su);
            stage64(fpW1b, nb * 64, 320, k0, Bs, wave, sr, su);
            __syncthreads();
            #pragma unroll
            for (int s = 0; s < 2; ++s) {
                bf16x8 a, b[2];
                {
                    const int r  = wr * 16 + (lane & 15);
                    const int lu = (s * 4 + (lane >> 4)) ^ (r & 7);
                    a = *reinterpret_cast<const bf16x8*>(&As[r * 64 + lu * 8]);
                }
                #pragma unroll
                for (int nf = 0; nf < 2; ++nf) {
                    const int r  = wc * 32 + nf * 16 + (lane & 15);
                    const int lu = (s * 4 + (lane >> 4)) ^ (r & 7);
                    b[nf] = *reinterpret_cast<const bf16x8*>(&Bs[r * 64 + lu * 8]);
                }
                #pragma unroll
                for (int nf = 0; nf < 2; ++nf)
                    acc[nf] = __builtin_amdgcn_mfma_f32_16x16x32_bf16(a, b[nf], acc[nf], 0, 0, 0);
            }
            __syncthreads();
        }
        #pragma unroll
        for (int nf = 0; nf < 2; ++nf) {
            const int col = wc * 32 + nf * 16 + (lane & 15);
            const float bv = fpb1[nb * 64 + col];
            #pragma unroll
            for (int i = 0; i < 4; ++i) {
                const int row = wr * 16 + (lane >> 4) * 4 + i;
                float v = fmaxf(acc[nf][i] + bv, 0.f);
                const int u = col >> 3;
                tpan[nb * 2048 + row * 64 + ((u ^ (row & 7)) * 8) + (col & 7)]
                    = (ushort_t)f2bf(v);
            }
        }
        __syncthreads();
    }

    // phase 2: side = fp2 . t2
    for (int nb = 0; nb < 5; ++nb) {
        f32x4 acc[2]; acc[0] = (f32x4)0.f; acc[1] = (f32x4)0.f;
        for (int kt = 0; kt < 5; ++kt) {
            stage64(fpW2b, nb * 64, 320, kt * 64, Bs, wave, sr, su);
            __syncthreads();
            #pragma unroll
            for (int s = 0; s < 2; ++s) {
                bf16x8 a, b[2];
                {
                    const int r  = wr * 16 + (lane & 15);
                    const int lu = (s * 4 + (lane >> 4)) ^ (r & 7);
                    a = *reinterpret_cast<const bf16x8*>(&tpan[kt * 2048 + r * 64 + lu * 8]);
                }
                #pragma unroll
                for (int nf = 0; nf < 2; ++nf) {
                    const int r  = wc * 32 + nf * 16 + (lane & 15);
                    const int lu = (s * 4 + (lane >> 4)) ^ (r & 7);
                    b[nf] = *reinterpret_cast<const bf16x8*>(&Bs[r * 64 + lu * 8]);
                }
                #pragma unroll
                for (int nf = 0; nf < 2; ++nf)
                    acc[nf] = __builtin_amdgcn_mfma_f32_16x16x32_bf16(a, b[nf], acc[nf], 0, 0, 0);
            }
            __syncthreads();
        }
        #pragma unroll
        for (int nf = 0; nf < 2; ++nf) {
            const int gn = nb * 64 + wc * 32 + nf * 16 + (lane & 15);
            const float bv = fpb2[gn];
            #pragma unroll
            for (int i = 0; i < 4; ++i) {
                const int gm = row0 + wr * 16 + (lane >> 4) * 4 + i;
                float v = acc[nf][i] + bv;
                out_side[(size_t)gm * 320 + gn] = v;
                sideB[(size_t)gm * 320 + gn] = (ushort_t)f2bf(v);
            }
        }
    }
}

// fusedC32: t3 = relu(pW1 . [bb|side]) (LDS panel, K=640) ;
//           c2 = relu(pW2 . t3) in regs ; refined = c2 . pW3 + pb3
__device__ void fusedC32_dev(
    int panel, const ushort_t* __restrict__ bbB, const ushort_t* __restrict__ sideB,
    const ushort_t* __restrict__ pW1b, const float* __restrict__ pb1,
    const ushort_t* __restrict__ pW2b, const float* __restrict__ pb2,
    const float* __restrict__ pW3, const float* __restrict__ pb3,
    float* __restrict__ out_ref, char* smem)
{
    ushort_t* tpan = (ushort_t*)smem;       // 20 KB
    ushort_t* As   = tpan + 5 * 2048;       // 4 KB
    ushort_t* Bs   = As + 2048;             // 8 KB
    float*    pSum = (float*)(Bs + 4096);   // [2][32][3]

    const int tid = threadIdx.x, wave = tid >> 6, lane = tid & 63;
    const int row0 = panel * 32;
    const int wr = wave >> 1, wc = wave & 1;
    const int sr = lane >> 3, su = lane & 7;

    for (int nb = 0; nb < 5; ++nb) {
        f32x4 acc[2]; acc[0] = (f32x4)0.f; acc[1] = (f32x4)0.f;
        for (int k0 = 0; k0 < 640; k0 += 64) {
            {
                const int r = wave * 8 + sr;
                const int gk = k0 + (su ^ (r & 7)) * 8;
                const ushort_t* src = (gk < 320)
                    ? bbB   + (size_t)(row0 + r) * 320 + gk
                    : sideB + (size_t)(row0 + r) * 320 + (gk - 320);
                __builtin_amdgcn_global_load_lds((gas_ptr)src, (las_ptr)&As[wave * 512], 16, 0, 0);
            }
            stage64(pW1b, nb * 64, 640, k0, Bs, wave, sr, su);
            __syncthreads();
            #pragma unroll
            for (int s = 0; s < 2; ++s) {
                bf16x8 a, b[2];
                {
                    const int r  = wr * 16 + (lane & 15);
                    const int lu = (s * 4 + (lane >> 4)) ^ (r & 7);
                    a = *reinterpret_cast<const bf16x8*>(&As[r * 64 + lu * 8]);
                }
                #pragma unroll
                for (int nf = 0; nf < 2; ++nf) {
                    const int r  = wc * 32 + nf * 16 + (lane & 15);
                    const int lu = (s * 4 + (lane >> 4)) ^ (r & 7);
                    b[nf] = *reinterpret_cast<const bf16x8*>(&Bs[r * 64 + lu * 8]);
                }
                #pragma unroll
                for (int nf = 0; nf < 2; ++nf)
                    acc[nf] = __builtin_amdgcn_mfma_f32_16x16x32_bf16(a, b[nf], acc[nf], 0, 0, 0);
            }
            __syncthreads();
        }
        #pragma unroll
        for (int nf = 0; nf < 2; ++nf) {
            const int col = wc * 32 + nf * 16 + (lane & 15);
            const float bv = pb1[nb * 64 + col];
            #pragma unroll
            for (int i = 0; i < 4; ++i) {
                const int row = wr * 16 + (lane >> 4) * 4 + i;
                float v = fmaxf(acc[nf][i] + bv, 0.f);
                const int u = col >> 3;
                tpan[nb * 2048 + row * 64 + ((u ^ (row & 7)) * 8) + (col & 7)]
                    = (ushort_t)f2bf(v);
            }
        }
        __syncthreads();
    }

    float part[4][3];
    #pragma unroll
    for (int i = 0; i < 4; ++i) { part[i][0] = part[i][1] = part[i][2] = 0.f; }

    for (int ct = 0; ct < 5; ++ct) {
        f32x4 acc = (f32x4)0.f;
        for (int kt = 0; kt < 5; ++kt) {
            stage32(pW2b, ct * 32, 320, kt * 64, Bs, wave, sr, su);
            __syncthreads();
            #pragma unroll
            for (int s = 0; s < 2; ++s) {
                bf16x8 a, b;
                {
                    const int r  = wr * 16 + (lane & 15);
                    const int lu = (s * 4 + (lane >> 4)) ^ (r & 7);
                    a = *reinterpret_cast<const bf16x8*>(&tpan[kt * 2048 + r * 64 + lu * 8]);
                }
                {
                    const int r  = wc * 16 + (lane & 15);
                    const int lu = (s * 4 + (lane >> 4)) ^ (r & 7);
                    b = *reinterpret_cast<const bf16x8*>(&Bs[r * 64 + lu * 8]);
                }
                acc = __builtin_amdgcn_mfma_f32_16x16x32_bf16(a, b, acc, 0, 0, 0);
            }
            __syncthreads();
        }
        const int col = ct * 32 + wc * 16 + (lane & 15);
        const float bv = pb2[col];
        #pragma unroll
        for (int i = 0; i < 4; ++i) {
            float v = fmaxf(acc[i] + bv, 0.f);
            #pragma unroll
            for (int n = 0; n < 3; ++n)
                part[i][n] += v * pW3[n * 160 + col];
        }
    }
    #pragma unroll
    for (int off = 8; off; off >>= 1)
        #pragma unroll
        for (int i = 0; i < 4; ++i)
            #pragma unroll
            for (int n = 0; n < 3; ++n)
                part[i][n] += __shfl_xor(part[i][n], off, 16);
    if ((lane & 15) == 0) {
        #pragma unroll
        for (int i = 0; i < 4; ++i) {
            const int row = wr * 16 + (lane >> 4) * 4 + i;
            #pragma unroll
            for (int n = 0; n < 3; ++n)
                pSum[(wc * 32 + row) * 3 + n] = part[i][n];
        }
    }
    __syncthreads();
    if (tid < 96) {
        const int row = tid / 3, n = tid % 3;
        out_ref[(size_t)(row0 + row) * 3 + n] =
            pSum[row * 3 + n] + pSum[(32 + row) * 3 + n] + pb3[n];
    }
}

// fusedD32: phase0 ao = Wo . ctx + bo -> LDS panel;
//           phase1 c1 = relu(mW1 . ao), prob = c1 . mW2 + mb2, contact rows.
__device__ void fusedD32_dev(
    int panel, const ushort_t* __restrict__ ctxb,
    const ushort_t* __restrict__ Wob, const float* __restrict__ bo,
    const ushort_t* __restrict__ mW1b, const float* __restrict__ mb1,
    const float* __restrict__ mW2, const float* __restrict__ mb2,
    float* __restrict__ out_cm, char* smem)
{
    ushort_t* tpan = (ushort_t*)smem;       // ao panel, 20 KB
    ushort_t* As   = tpan + 5 * 2048;       // 4 KB
    ushort_t* Bs   = As + 2048;             // 8 KB
    float*    pSum = (float*)(Bs + 4096);   // [2][32]
    float*    probs= pSum + 64;             // [32]

    const int tid = threadIdx.x, wave = tid >> 6, lane = tid & 63;
    const int row0 = panel * 32;
    const int wr = wave >> 1, wc = wave & 1;
    const int sr = lane >> 3, su = lane & 7;

    for (int nb = 0; nb < 5; ++nb) {
        f32x4 acc[2]; acc[0] = (f32x4)0.f; acc[1] = (f32x4)0.f;
        for (int k0 = 0; k0 < 320; k0 += 64) {
            stage32(ctxb, row0,    320, k0, As, wave, sr, su);
            stage64(Wob,  nb * 64, 320, k0, Bs, wave, sr, su);
            __syncthreads();
            #pragma unroll
            for (int s = 0; s < 2; ++s) {
                bf16x8 a, b[2];
                {
                    const int r  = wr * 16 + (lane & 15);
                    const int lu = (s * 4 + (lane >> 4)) ^ (r & 7);
                    a = *reinterpret_cast<const bf16x8*>(&As[r * 64 + lu * 8]);
                }
                #pragma unroll
                for (int nf = 0; nf < 2; ++nf) {
                    const int r  = wc * 32 + nf * 16 + (lane & 15);
                    const int lu = (s * 4 + (lane >> 4)) ^ (r & 7);
                    b[nf] = *reinterpret_cast<const bf16x8*>(&Bs[r * 64 + lu * 8]);
                }
                #pragma unroll
                for (int nf = 0; nf < 2; ++nf)
                    acc[nf] = __builtin_amdgcn_mfma_f32_16x16x32_bf16(a, b[nf], acc[nf], 0, 0, 0);
            }
            __syncthreads();
        }
        #pragma unroll
        for (int nf = 0; nf < 2; ++nf) {
            const int col = wc * 32 + nf * 16 + (lane & 15);
            const float bv = bo[nb * 64 + col];
            #pragma unroll
            for (int i = 0; i < 4; ++i) {
                const int row = wr * 16 + (lane >> 4) * 4 + i;
                float v = acc[nf][i] + bv;
                const int u = col >> 3;
                tpan[nb * 2048 + row * 64 + ((u ^ (row & 7)) * 8) + (col & 7)]
                    = (ushort_t)f2bf(v);
            }
        }
        __syncthreads();
    }

    float part[4] = {0.f, 0.f, 0.f, 0.f};
    for (int ct = 0; ct < 5; ++ct) {
        f32x4 acc = (f32x4)0.f;
        for (int kt = 0; kt < 5; ++kt) {
            stage32(mW1b, ct * 32, 320, kt * 64, Bs, wave, sr, su);
            __syncthreads();
            #pragma unroll
            for (int s = 0; s < 2; ++s) {
                bf16x8 a, b;
                {
                    const int r  = wr * 16 + (lane & 15);
                    const int lu = (s * 4 + (lane >> 4)) ^ (r & 7);
                    a = *reinterpret_cast<const bf16x8*>(&tpan[kt * 2048 + r * 64 + lu * 8]);
                }
                {
                    const int r  = wc * 16 + (lane & 15);
                    const int lu = (s * 4 + (lane >> 4)) ^ (r & 7);
                    b = *reinterpret_cast<const bf16x8*>(&Bs[r * 64 + lu * 8]);
                }
                acc = __builtin_amdgcn_mfma_f32_16x16x32_bf16(a, b, acc, 0, 0, 0);
            }
            __syncthreads();
        }
        const int col = ct * 32 + wc * 16 + (lane & 15);
        const float bv = mb1[col];
        const float w  = mW2[col];
        #pragma unroll
        for (int i = 0; i < 4; ++i)
            part[i] += fmaxf(acc[i] + bv, 0.f) * w;
    }
    #pragma unroll
    for (int off = 8; off; off >>= 1)
        #pragma unroll
        for (int i = 0; i < 4; ++i)
            part[i] += __shfl_xor(part[i], off, 16);
    if ((lane & 15) == 0) {
        #pragma unroll
        for (int i = 0; i < 4; ++i) {
            const int row = wr * 16 + (lane >> 4) * 4 + i;
            pSum[wc * 32 + row] = part[i];
        }
    }
    __syncthreads();
    if (tid < 32) probs[tid] = pSum[tid] + pSum[32 + tid] + mb2[0];
    __syncthreads();

    for (int r = 0; r < 32; ++r) {
        const float p = probs[r];
        reinterpret_cast<float4*>(out_cm + (size_t)(row0 + r) * 1024)[tid] =
            make_float4(p, p, p, p);
    }
}

// ================================ kernels ===================================

struct ConvDesc { const float* src; ushort_t* dst; };
struct ConvPack { ConvDesc d[5]; int start[6]; };

// 8 floats (32B) per thread -> 2048 floats per block
__device__ __forceinline__ void conv_unit(const ConvPack& p, int u, int tid)
{
    int i = 0;
    #pragma unroll
    for (int t = 0; t < 5; ++t) if (u >= p.start[t + 1]) i = t + 1;
    const int idx = ((u - p.start[i]) * 256 + tid) * 8;
    float4 v0 = *reinterpret_cast<const float4*>(&p.d[i].src[idx]);
    float4 v1 = *reinterpret_cast<const float4*>(&p.d[i].src[idx + 4]);
    uint4 pk;
    pk.x = f2bf(v0.x) | (f2bf(v0.y) << 16);
    pk.y = f2bf(v0.z) | (f2bf(v0.w) << 16);
    pk.z = f2bf(v1.x) | (f2bf(v1.y) << 16);
    pk.w = f2bf(v1.z) | (f2bf(v1.w) << 16);
    *reinterpret_cast<uint4*>(&p.d[i].dst[idx]) = pk;
}

__global__ __launch_bounds__(256) void conv_k(ConvPack p)
{
    conv_unit(p, blockIdx.x, threadIdx.x);
}

// G1: x -> [fp1(relu) | q | k | v], N=1280, XCD-aware panel map (verified r11).
// Blocks [2560, 2560+250): convert the 5 weight matrices later stages need.
__global__ __launch_bounds__(256) void k_g1(
    const ushort_t* __restrict__ xb, const ushort_t* __restrict__ Wcat,
    const float* __restrict__ fpb1, const float* __restrict__ bq,
    const float* __restrict__ bk, const float* __restrict__ bvv,
    ushort_t* __restrict__ t1b, ushort_t* __restrict__ qkvb, ConvPack cp)
{
    __shared__ __align__(16) char smem[24 * 1024];
    const int bid = blockIdx.x;
    if (bid >= 2560) { conv_unit(cp, bid - 2560, threadIdx.x); return; }

    const int xcd = bid & 7;
    const int i0  = bid >> 3;            // 0..319
    const int ty  = xcd * 16 + i0 / 20;  // 0..127
    const int tx  = i0 % 20;

    f32x4 acc[4][2];
    #pragma unroll
    for (int i = 0; i < 4; ++i) { acc[i][0] = (f32x4)0.f; acc[i][1] = (f32x4)0.f; }
    gemm_core<64>(tx, ty, xb, xb, 320, 320, Wcat, smem, acc);

    const int tid = threadIdx.x, wave = tid >> 6, lane = tid & 63;
    const int wr = wave >> 1, wc = wave & 1;
    #pragma unroll
    for (int nf = 0; nf < 2; ++nf) {
        const int gn = tx * 64 + wc * 32 + nf * 16 + (lane & 15);
        float bv;
        if      (gn < 320) bv = fpb1[gn];
        else if (gn < 640) bv = bq[gn - 320];
        else if (gn < 960) bv = bk[gn - 640];
        else               bv = bvv[gn - 960];
        #pragma unroll
        for (int mf = 0; mf < 4; ++mf) {
            #pragma unroll
            for (int i = 0; i < 4; ++i) {
                const int gm = ty * 128 + wr * 64 + mf * 16 + (lane >> 4) * 4 + i;
                float v = acc[mf][nf][i] + bv;
                if (gn < 320) t1b [(size_t)gm * 320 + gn] = (ushort_t)f2bf(fmaxf(v, 0.f));
                else          qkvb[(size_t)gm * 960 + gn - 320] = (ushort_t)f2bf(v);
            }
        }
    }
}

// L2: [0,512) G2B (bb->t2->side, XCD-aligned panel), [512,8704) attention
__global__ __launch_bounds__(256) void k_l2(
    const ushort_t* __restrict__ t1b,
    const ushort_t* __restrict__ fpW1b, const float* __restrict__ fpb1,
    const ushort_t* __restrict__ fpW2b, const float* __restrict__ fpb2,
    float* __restrict__ out_bb, ushort_t* __restrict__ bbB,
    float* __restrict__ out_side, ushort_t* __restrict__ sideB,
    const ushort_t* __restrict__ qkvb, ushort_t* __restrict__ ctxb)
{
    __shared__ __align__(16) char smem[33 * 1024];
    const int bid = blockIdx.x;
    if (bid < 512) {
        // panel p on XCD p/64 == the XCD that wrote t1 rows [32p,32p+32)
        const int p = (bid & 7) * 64 + (bid >> 3);
        g2b_dev(p, t1b, fpW1b, fpb1, fpW2b, fpb2,
                out_bb, bbB, out_side, sideB, smem);
    } else {
        attn_dev(bid - 512, qkvb, ctxb, smem);
    }
}

// L3: [0,512) fusedC32 (refined, XCD-aligned), [512,1024) fusedD32 (contact, XCD-aligned)
__global__ __launch_bounds__(256) void k_l3(
    const ushort_t* __restrict__ bbB, const ushort_t* __restrict__ sideB,
    const ushort_t* __restrict__ pW1b, const float* __restrict__ pb1,
    const ushort_t* __restrict__ pW2b, const float* __restrict__ pb2,
    const float* __restrict__ pW3, const float* __restrict__ pb3,
    float* __restrict__ out_ref,
    const ushort_t* __restrict__ ctxb,
    const ushort_t* __restrict__ Wob, const float* __restrict__ bo,
    const ushort_t* __restrict__ mW1b, const float* __restrict__ mb1,
    const float* __restrict__ mW2, const float* __restrict__ mb2,
    float* __restrict__ out_cm)
{
    __shared__ __align__(16) char smem[34 * 1024];
    const int bid = blockIdx.x;
    if (bid < 512) {
        const int p = (bid & 7) * 64 + (bid >> 3);
        fusedC32_dev(p, bbB, sideB, pW1b, pb1, pW2b, pb2, pW3, pb3, out_ref, smem);
    } else {
        const int b = bid - 512;
        const int p = (b & 7) * 64 + (b >> 3);
        fusedD32_dev(p, ctxb, Wob, bo, mW1b, mb1, mW2, mb2, out_cm, smem);
    }
}

extern "C" void kernel_launch(void* const* d_in, const int* in_sizes, int n_in,
                              void* d_out, int out_size, void* d_ws, size_t ws_size,
                              hipStream_t stream)
{
    const float* x    = (const float*)d_in[0];
    const float* fpW1 = (const float*)d_in[1];
    const float* fpb1 = (const float*)d_in[2];
    const float* fpW2 = (const float*)d_in[3];
    const float* fpb2 = (const float*)d_in[4];
    const float* Wq   = (const float*)d_in[5];
    const float* bq   = (const float*)d_in[6];
    const float* Wk   = (const float*)d_in[7];
    const float* bk   = (const float*)d_in[8];
    const float* Wv   = (const float*)d_in[9];
    const float* bv   = (const float*)d_in[10];
    const float* Wo   = (const float*)d_in[11];
    const float* bo   = (const float*)d_in[12];
    const float* mW1  = (const float*)d_in[13];
    const float* mb1  = (const float*)d_in[14];
    const float* mW2  = (const float*)d_in[15];
    const float* mb2  = (const float*)d_in[16];
    const float* pW1  = (const float*)d_in[17];
    const float* pb1  = (const float*)d_in[18];
    const float* pW2  = (const float*)d_in[19];
    const float* pb2  = (const float*)d_in[20];
    const float* pW3  = (const float*)d_in[21];
    const float* pb3  = (const float*)d_in[22];

    float* out      = (float*)d_out;
    float* out_bb   = out;
    float* out_side = out + 5242880;
    float* out_cm   = out + 2 * 5242880;
    float* out_ref  = out + 2 * 5242880 + 16777216;

    ushort_t* ws = (ushort_t*)d_ws;
    const size_t BUF = 5242880;
    ushort_t* xb    = ws;              // x bf16; later ctx
    ushort_t* t1b   = ws + 1 * BUF;    // fp1(x) relu
    ushort_t* bbB   = ws + 2 * BUF;
    ushort_t* sideB = ws + 3 * BUF;
    ushort_t* qkvb  = ws + 4 * BUF;    // [M,960] spans 3 BUFs
    ushort_t* wb    = ws + 7 * BUF;
    ushort_t* fpW1b = wb;              // Wcat = [fpW1|Wq|Wk|Wv] contiguous
    ushort_t* Wqb   = wb + 102400;
    ushort_t* Wkb   = wb + 204800;
    ushort_t* Wvb   = wb + 307200;
    ushort_t* fpW2b = wb + 409600;
    ushort_t* Wob   = wb + 512000;
    ushort_t* mW1b  = wb + 614400;
    ushort_t* pW1b  = wb + 665600;
    ushort_t* pW2b  = wb + 870400;

    ushort_t* ctxb = xb;               // alias (x dead after L1)

    dim3 blk(256);

    // L0: convert x + Wcat (8 floats/thread -> 2048 floats/block)
    ConvPack cp0;
    {
        const float* s[5] = {x, fpW1, Wq, Wk, Wv};
        ushort_t*    d[5] = {xb, fpW1b, Wqb, Wkb, Wvb};
        const int    n[5] = {2560, 50, 50, 50, 50};
        int a = 0;
        for (int i = 0; i < 5; ++i) { cp0.d[i] = {s[i], d[i]}; cp0.start[i] = a; a += n[i]; }
        cp0.start[5] = a;   // 2760
    }
    conv_k<<<dim3(2760), blk, 0, stream>>>(cp0);

    // L1: G1 (2560, XCD-aware) || convert remaining 5 weight matrices (250)
    ConvPack cp1;
    {
        const float* s[5] = {fpW2, Wo, mW1, pW1, pW2};
        ushort_t*    d[5] = {fpW2b, Wob, mW1b, pW1b, pW2b};
        const int    n[5] = {50, 50, 25, 100, 25};
        int a = 0;
        for (int i = 0; i < 5; ++i) { cp1.d[i] = {s[i], d[i]}; cp1.start[i] = a; a += n[i]; }
        cp1.start[5] = a;   // 250
    }
    k_g1<<<dim3(2560 + 250), blk, 0, stream>>>(xb, wb, fpb1, bq, bk, bv, t1b, qkvb, cp1);

    // L2: G2B (XCD-aligned panels) || attention
    k_l2<<<dim3(8704), blk, 0, stream>>>(t1b, fpW1b, fpb1, fpW2b, fpb2,
                                         out_bb, bbB, out_side, sideB, qkvb, ctxb);
    // L3: fusedC32 || fusedD32 (XCD-aligned panels)
    k_l3<<<dim3(1024), blk, 0, stream>>>(bbB, sideB, pW1b, pb1, pW2b, pb2, pW3, pb3,
                                         out_ref, ctxb, Wob, bo, mW1b, mb1, mW2, mb2, out_cm);
}